// Round 9
// baseline (140.154 us; speedup 1.0000x reference)
//
#include <hip/hip_runtime.h>

// CustomAttention: x[2,2048,1024] f32, w_qkv[3072,1024], w_proj[1024,1024], b_proj[1024]
// Round 9: attention arithmetic-intensity restructure: 8 waves x 32 q-rows (2 Q-sets
//          in registers) -> each K/V fragment read feeds 2 MFMAs; 256 q per block,
//          grid 256 (1 block/CU, KV L2-resident per XCD); __launch_bounds__(512,2)
//          for a 256-VGPR budget (addresses stay live). GEMMs unchanged (round 7).
//   k0: convert_f16: x, w_qkv, w_proj f32 -> f16
//   k1: gemm128<0>: qkv -> Qd bf16 (scaled 0.125*log2e), Kd bf16, Vt bf16 [bh][d][n]
//   k2: attn_mfma -> AO f16 [b][n][C]
//   k3: gemm128<1>: proj + bias -> d_out f32

constexpr int B_ = 2, N_ = 2048, C_ = 1024, H_ = 16, D_ = 64;
constexpr int M_ = B_ * N_;   // 4096
constexpr int O3 = 3 * C_;    // 3072
constexpr int KVB = 64;
constexpr int NTILES = N_ / KVB;   // 32

typedef short bf16x8 __attribute__((ext_vector_type(8)));
typedef _Float16 half8 __attribute__((ext_vector_type(8)));
typedef _Float16 half4v __attribute__((ext_vector_type(4)));
typedef float f32x4  __attribute__((ext_vector_type(4)));

__device__ __forceinline__ unsigned short f2bf(float f) {
    unsigned int u = __float_as_uint(f);
    unsigned int r = (u + 0x7FFFu + ((u >> 16) & 1u)) >> 16;
    return (unsigned short)r;
}

__device__ __forceinline__ void async16(const void* g, void* l) {
    __builtin_amdgcn_global_load_lds(
        (const __attribute__((address_space(1))) unsigned int*)g,
        (__attribute__((address_space(3))) unsigned int*)l, 16, 0, 0);
}

// ---------------- f32 -> f16 convert (x | w_qkv | w_proj) ----------------
constexpr size_t XN  = (size_t)M_ * C_;        // 4,194,304
constexpr size_t WQN = (size_t)O3 * C_;        // 3,145,728
constexpr size_t WPN = (size_t)C_ * C_;        // 1,048,576

__global__ __launch_bounds__(256)
void convert_f16(const float* __restrict__ x, const float* __restrict__ wq,
                 const float* __restrict__ wp, _Float16* __restrict__ dst)
{
    size_t i = ((size_t)blockIdx.x * 256 + threadIdx.x) * 8;
    const float* src;
    size_t off;
    if (i < XN)            { src = x;  off = i; }
    else if (i < XN + WQN) { src = wq; off = i - XN; }
    else                   { src = wp; off = i - XN - WQN; }
    float4 a = *(const float4*)(src + off);
    float4 b = *(const float4*)(src + off + 4);
    half8 h;
    h[0] = (_Float16)a.x; h[1] = (_Float16)a.y; h[2] = (_Float16)a.z; h[3] = (_Float16)a.w;
    h[4] = (_Float16)b.x; h[5] = (_Float16)b.y; h[6] = (_Float16)b.z; h[7] = (_Float16)b.w;
    *(half8*)(dst + i) = h;
}

// ---------------- f16 MFMA GEMM: 128x128 tile, BK=64, coalesced staging ----------
template<int MODE>
__global__ __launch_bounds__(256)
void gemm128(const _Float16* __restrict__ Ag, const _Float16* __restrict__ Bg,
             unsigned short* __restrict__ Qd, unsigned short* __restrict__ Kd,
             unsigned short* __restrict__ Vt,
             const float* __restrict__ bias, float* __restrict__ Out)
{
    __shared__ __align__(16) unsigned char Ab[2][16384];
    __shared__ __align__(16) unsigned char Bb[2][16384];

    const int t    = threadIdx.x;
    const int lane = t & 63;
    const int w    = t >> 6;
    const int g    = lane >> 4;
    const int c    = lane & 15;
    const int wm   = w >> 1, wn = w & 1;
    const int bm   = blockIdx.y * 128;
    const int bn   = blockIdx.x * 128;
    constexpr int K = C_;

    f32x4 acc[4][4];
    f32x4 zero = {0.f, 0.f, 0.f, 0.f};
    #pragma unroll
    for (int mi = 0; mi < 4; ++mi)
        #pragma unroll
        for (int ni = 0; ni < 4; ++ni) acc[mi][ni] = zero;

    auto stage = [&](int buf, int k0) {
        #pragma unroll
        for (int i = 0; i < 4; ++i) {
            int id  = t + 256 * i;        // 0..1023 = row*8 + p
            int row = id >> 3;
            int p   = id & 7;
            int gs  = p ^ (row & 7);      // pre-swizzled source granule
            async16(Ag + (size_t)(bm + row) * K + k0 + 8 * gs, &Ab[buf][id * 16]);
            async16(Bg + (size_t)(bn + row) * K + k0 + 8 * gs, &Bb[buf][id * 16]);
        }
    };

    stage(0, 0);
    __syncthreads();
    int cur = 0;

    for (int k0 = 0; k0 < K; k0 += 64) {
        if (k0 + 64 < K) stage(cur ^ 1, k0 + 64);   // prefetch next tile

        const unsigned char* Abase = Ab[cur];
        const unsigned char* Bbase = Bb[cur];
        #pragma unroll
        for (int s = 0; s < 2; ++s) {               // two k-slices of 32
            half8 af[4], bf[4];
            #pragma unroll
            for (int mi = 0; mi < 4; ++mi) {
                int row = wm * 64 + mi * 16 + c;
                af[mi] = *(const half8*)(Abase + (row * 8 + ((s * 4 + g) ^ (row & 7))) * 16);
            }
            #pragma unroll
            for (int ni = 0; ni < 4; ++ni) {
                int row = wn * 64 + ni * 16 + c;
                bf[ni] = *(const half8*)(Bbase + (row * 8 + ((s * 4 + g) ^ (row & 7))) * 16);
            }
            #pragma unroll
            for (int mi = 0; mi < 4; ++mi)
                #pragma unroll
                for (int ni = 0; ni < 4; ++ni)
                    acc[mi][ni] = __builtin_amdgcn_mfma_f32_16x16x32_f16(af[mi], bf[ni], acc[mi][ni], 0, 0, 0);
        }

        __syncthreads();   // drains this iter's prefetch + protects buffer swap
        cur ^= 1;
    }

    if constexpr (MODE == 0) {
        // scatter epilogue: o = which*1024 + h*64 + d (64-col wave region = one head)
        constexpr float QSCALE = 0.125f * 1.4426950408889634f;   // D^-0.5 * log2(e)
        const int o0 = bn + wn * 64;
        const int which = o0 >> 10;
        const int h  = (o0 & 1023) >> 6;
        const int m0 = bm + wm * 64;
        const int b  = m0 >> 11;
        const int n0 = m0 & 2047;
        const size_t bh = (size_t)b * H_ + h;
        if (which == 0) {
            unsigned short* base = Qd + (bh * N_) * D_;
            #pragma unroll
            for (int mi = 0; mi < 4; ++mi)
                #pragma unroll
                for (int ni = 0; ni < 4; ++ni)
                    #pragma unroll
                    for (int r = 0; r < 4; ++r)
                        base[(size_t)(n0 + mi * 16 + 4 * g + r) * D_ + ni * 16 + c] =
                            f2bf(acc[mi][ni][r] * QSCALE);
        } else if (which == 1) {
            unsigned short* base = Kd + (bh * N_) * D_;
            #pragma unroll
            for (int mi = 0; mi < 4; ++mi)
                #pragma unroll
                for (int ni = 0; ni < 4; ++ni)
                    #pragma unroll
                    for (int r = 0; r < 4; ++r)
                        base[(size_t)(n0 + mi * 16 + 4 * g + r) * D_ + ni * 16 + c] =
                            f2bf(acc[mi][ni][r]);
        } else {
            unsigned short* base = Vt + (bh * D_) * (size_t)N_;
            #pragma unroll
            for (int mi = 0; mi < 4; ++mi)
                #pragma unroll
                for (int ni = 0; ni < 4; ++ni) {
                    ushort4 v;
                    v.x = f2bf(acc[mi][ni][0]);
                    v.y = f2bf(acc[mi][ni][1]);
                    v.z = f2bf(acc[mi][ni][2]);
                    v.w = f2bf(acc[mi][ni][3]);
                    *(ushort4*)&base[(size_t)(ni * 16 + c) * N_ + n0 + mi * 16 + 4 * g] = v;
                }
        }
    } else {
        const int m0 = bm + wm * 64;
        const int o0 = bn + wn * 64;
        #pragma unroll
        for (int ni = 0; ni < 4; ++ni) {
            float bb = bias[o0 + ni * 16 + c];
            #pragma unroll
            for (int mi = 0; mi < 4; ++mi)
                #pragma unroll
                for (int r = 0; r < 4; ++r)
                    Out[(size_t)(m0 + mi * 16 + 4 * g + r) * C_ + o0 + ni * 16 + c] =
                        acc[mi][ni][r] + bb;
        }
    }
}

// ---------------- MFMA flash attention: 8 waves x 32 q rows (256 q / block) ------
// Frags (16x16x32): A row=lane&15, k=8*(lane>>4)+e ; B col=lane&15 same k ;
// C/D col=lane&15, row=4*(lane>>4)+reg.
__global__ __launch_bounds__(512, 2)
void attn_mfma(const unsigned short* __restrict__ Qd, const unsigned short* __restrict__ Kd,
               const unsigned short* __restrict__ Vt, _Float16* __restrict__ AO)
{
    __shared__ __align__(16) unsigned char KsB[2][8192];   // K tile  [key][d] bf16, swz
    __shared__ __align__(16) unsigned char VtB[2][8192];   // V^T tile [d][key] bf16, swz
    __shared__ __align__(16) unsigned char Pb[8][4096];    // per-wave P, 2 q-sets x [16][64k]

    const int t    = threadIdx.x;
    const int lane = t & 63;
    const int w    = t >> 6;                 // 0..7
    const int g    = lane >> 4;
    const int c    = lane & 15;
    const int cx   = c & 7;

    // bijective XCD swizzle: 256 blocks, 32 works/XCD -> 4 consecutive bh per XCD
    int flat = blockIdx.x;
    int work = (flat & 7) * 32 + (flat >> 3);
    const int bh = work >> 3;               // 0..31
    const int qt = work & 7;                // 0..7
    const int b  = bh >> 4, h = bh & 15;
    const int q0 = qt * 256;

    const unsigned short* Kp = Kd + (size_t)bh * N_ * D_;
    const unsigned short* Vp = Vt + (size_t)bh * D_ * N_;

    // Q fragments: 2 q-sets of 16 rows each (q = q0 + w*32 + qs*16 + c)
    const unsigned short* qp = Qd + ((size_t)bh * N_ + q0 + w * 32 + c) * D_;
    bf16x8 qf[2][2];
    #pragma unroll
    for (int qs = 0; qs < 2; ++qs)
        #pragma unroll
        for (int s = 0; s < 2; ++s)
            qf[qs][s] = *(const bf16x8*)(qp + qs * 16 * D_ + s * 32 + 8 * g);

    // staging addresses (advance per tile)
    const int rk = t >> 3, pk = t & 7;
    const unsigned char* kSrc = (const unsigned char*)Kp + rk * 128 + ((pk ^ (rk & 7)) << 4);
    const unsigned char* vSrc = (const unsigned char*)Vp + (size_t)rk * N_ * 2 + ((pk ^ (rk & 7)) << 4);
    unsigned char* kDstA = KsB[0] + t * 16;
    unsigned char* kDstB = KsB[1] + t * 16;
    unsigned char* vDstA = VtB[0] + t * 16;
    unsigned char* vDstB = VtB[1] + t * 16;

    // ones-row A-fragment for the denominator MFMA (row 64 of virtual V^T)
    bf16x8 aone;
    {
        short onev = (c == 0) ? (short)0x3F80 : (short)0;
        #pragma unroll
        for (int e = 0; e < 8; ++e) aone[e] = onev;
    }

    float m_run[2] = {-1e30f, -1e30f};
    f32x4 oc[2][4];
    f32x4 lsum[2];
    f32x4 zero = {0.f, 0.f, 0.f, 0.f};
    #pragma unroll
    for (int qs = 0; qs < 2; ++qs) {
        lsum[qs] = zero;
        #pragma unroll
        for (int dc = 0; dc < 4; ++dc) oc[qs][dc] = zero;
    }

    async16(kSrc, kDstA);
    async16(vSrc, vDstA);
    __syncthreads();

    auto tile_body = [&](const unsigned char* kbase, const unsigned char* vb,
                         unsigned char* kDstN, unsigned char* vDstN, int ktNext) {
        if (ktNext < NTILES) {
            async16(kSrc + (size_t)ktNext * KVB * 128, kDstN);
            async16(vSrc + (size_t)ktNext * 128, vDstN);
        }

        // ---- S^T = K * Q^T : each K-frag feeds both q-sets ----
        f32x4 st[2][4];
        #pragma unroll
        for (int qs = 0; qs < 2; ++qs)
            #pragma unroll
            for (int tt = 0; tt < 4; ++tt) st[qs][tt] = zero;
        __builtin_amdgcn_s_setprio(1);
        #pragma unroll
        for (int s = 0; s < 2; ++s) {
            #pragma unroll
            for (int tt = 0; tt < 4; ++tt) {
                bf16x8 a = *(const bf16x8*)(kbase + (tt * 16 + c) * 128 + (((4 * s + g) ^ cx) << 4));
                st[0][tt] = __builtin_amdgcn_mfma_f32_16x16x32_bf16(a, qf[0][s], st[0][tt], 0, 0, 0);
                st[1][tt] = __builtin_amdgcn_mfma_f32_16x16x32_bf16(a, qf[1][s], st[1][tt], 0, 0, 0);
            }
        }
        __builtin_amdgcn_s_setprio(0);

        // ---- per-q-set tile max (max3 tree + 2 cross-lane) ----
        float mx[2];
        #pragma unroll
        for (int qs = 0; qs < 2; ++qs) {
            float t0 = fmaxf(fmaxf(st[qs][0][0], st[qs][0][1]), st[qs][0][2]);
            float t1 = fmaxf(fmaxf(st[qs][0][3], st[qs][1][0]), st[qs][1][1]);
            float t2 = fmaxf(fmaxf(st[qs][1][2], st[qs][1][3]), st[qs][2][0]);
            float t3 = fmaxf(fmaxf(st[qs][2][1], st[qs][2][2]), st[qs][2][3]);
            float t4 = fmaxf(fmaxf(st[qs][3][0], st[qs][3][1]), st[qs][3][2]);
            float m  = fmaxf(fmaxf(fmaxf(t0, t1), fmaxf(t2, t3)), fmaxf(t4, st[qs][3][3]));
            m = fmaxf(m, __shfl_xor(m, 16));
            m = fmaxf(m, __shfl_xor(m, 32));
            mx[qs] = m;
        }

        // ---- defer-max (THR = 8 in log2 domain) ----
        const bool defer = __all(fmaxf(mx[0] - m_run[0], mx[1] - m_run[1]) <= 8.f);
        if (!defer) {
            #pragma unroll
            for (int qs = 0; qs < 2; ++qs) {
                const float nm = fmaxf(m_run[qs], mx[qs]);
                const float corr = exp2f(m_run[qs] - nm);
                m_run[qs] = nm;
                #pragma unroll
                for (int dc = 0; dc < 4; ++dc) oc[qs][dc] *= corr;
                lsum[qs][0] *= corr;
            }
        }
        #pragma unroll
        for (int qs = 0; qs < 2; ++qs)
            #pragma unroll
            for (int tt = 0; tt < 4; ++tt)
                #pragma unroll
                for (int r = 0; r < 4; ++r)
                    st[qs][tt][r] = exp2f(st[qs][tt][r] - m_run[qs]);

        // ---- pack P (truncate to bf16) -> wave-private LDS, per q-set ----
        #pragma unroll
        for (int qs = 0; qs < 2; ++qs) {
            unsigned char* pwq = Pb[w] + qs * 2048 + c * 128;
            #pragma unroll
            for (int tt = 0; tt < 4; ++tt) {
                unsigned int lo = __byte_perm(__float_as_uint(st[qs][tt][0]), __float_as_uint(st[qs][tt][1]), 0x7632);
                unsigned int hi = __byte_perm(__float_as_uint(st[qs][tt][2]), __float_as_uint(st[qs][tt][3]), 0x7632);
                int gran = 2 * tt + (g >> 1);
                unsigned int* dst = (unsigned int*)(pwq + ((gran ^ cx) << 4) + 8 * (g & 1));
                dst[0] = lo;
                dst[1] = hi;
            }
        }

        // ---- out^T += V^T * P : each V-frag feeds both q-sets; lsum rides along ----
        const unsigned char* prd = Pb[w] + c * 128;
        __builtin_amdgcn_s_setprio(1);
        #pragma unroll
        for (int s = 0; s < 2; ++s) {
            bf16x8 pb0 = *(const bf16x8*)(prd + (((s * 4 + g) ^ cx) << 4));
            bf16x8 pb1 = *(const bf16x8*)(prd + 2048 + (((s * 4 + g) ^ cx) << 4));
            #pragma unroll
            for (int dc = 0; dc < 4; ++dc) {
                bf16x8 a = *(const bf16x8*)(vb + (dc * 16 + c) * 128 + (((s * 4 + g) ^ cx) << 4));
                oc[0][dc] = __builtin_amdgcn_mfma_f32_16x16x32_bf16(a, pb0, oc[0][dc], 0, 0, 0);
                oc[1][dc] = __builtin_amdgcn_mfma_f32_16x16x32_bf16(a, pb1, oc[1][dc], 0, 0, 0);
            }
            lsum[0] = __builtin_amdgcn_mfma_f32_16x16x32_bf16(aone, pb0, lsum[0], 0, 0, 0);
            lsum[1] = __builtin_amdgcn_mfma_f32_16x16x32_bf16(aone, pb1, lsum[1], 0, 0, 0);
        }
        __builtin_amdgcn_s_setprio(0);

        __syncthreads();   // drains vmcnt (stage done) + protects buffer swap
    };

    #pragma unroll 1
    for (int kt = 0; kt < NTILES; kt += 2) {
        tile_body(KsB[0], VtB[0], kDstB, vDstB, kt + 1);
        tile_body(KsB[1], VtB[1], kDstA, vDstA, kt + 2);
    }

    // ---- epilogue: l broadcast from lane c (row 64 = g0/reg0), normalize, store ----
    #pragma unroll
    for (int qs = 0; qs < 2; ++qs) {
        float l = __shfl(lsum[qs][0], c);
        float inv = 1.0f / l;
        int q = q0 + w * 32 + qs * 16 + c;
        _Float16* aop = AO + ((size_t)b * N_ + q) * C_ + h * D_;
        #pragma unroll
        for (int dc = 0; dc < 4; ++dc) {
            half4v o;
            o[0] = (_Float16)(oc[qs][dc][0] * inv);
            o[1] = (_Float16)(oc[qs][dc][1] * inv);
            o[2] = (_Float16)(oc[qs][dc][2] * inv);
            o[3] = (_Float16)(oc[qs][dc][3] * inv);
            *(half4v*)(aop + dc * 16 + 4 * g) = o;
        }
    }
}

extern "C" void kernel_launch(void* const* d_in, const int* in_sizes, int n_in,
                              void* d_out, int out_size, void* d_ws, size_t ws_size,
                              hipStream_t stream) {
    const float* x      = (const float*)d_in[0];
    const float* w_qkv  = (const float*)d_in[1];
    const float* w_proj = (const float*)d_in[2];
    const float* b_proj = (const float*)d_in[3];
    float* out = (float*)d_out;

    const size_t hd = (size_t)B_ * H_ * N_ * D_;   // 4,194,304 elems
    unsigned short* Qd = (unsigned short*)d_ws;
    unsigned short* Kd = Qd + hd;
    unsigned short* Vt = Kd + hd;
    _Float16* AO  = (_Float16*)(Vt + hd);          // [B,N,C] f16
    _Float16* x16 = AO + hd;                       // [4096][1024]
    _Float16* wq16 = x16 + XN;                     // [3072][1024]
    _Float16* wp16 = wq16 + WQN;                   // [1024][1024]

    convert_f16<<<4096, 256, 0, stream>>>(x, w_qkv, w_proj, x16);
    gemm128<0><<<dim3(O3 / 128, M_ / 128), 256, 0, stream>>>(
        x16, wq16, Qd, Kd, Vt, nullptr, nullptr);
    attn_mfma<<<dim3(256), 512, 0, stream>>>(Qd, Kd, Vt, AO);
    gemm128<1><<<dim3(C_ / 128, M_ / 128), 256, 0, stream>>>(
        AO, wp16, nullptr, nullptr, nullptr, b_proj, out);
}

// Round 10
// 140.026 us; speedup vs baseline: 1.0009x; 1.0009x over previous
//
#include <hip/hip_runtime.h>

// CustomAttention: x[2,2048,1024] f32, w_qkv[3072,1024], w_proj[1024,1024], b_proj[1024]
// Round 10: attention rewritten on 32x32x16 MFMA: 4 waves x 32 q-rows, grid 512.
//           P->PV redistribution fully in-register via cvt_pk(byte_perm) +
//           v_permlane32_swap_b32 (no P LDS). Softmax denom via VALU sum.
//           LDS 32KB (K/V^T dbuf only). GEMMs unchanged from round 7.
//   k0: convert_f16: x, w_qkv, w_proj f32 -> f16
//   k1: gemm128<0>: qkv -> Qd bf16 (scaled 0.125*log2e), Kd bf16, Vt bf16 [bh][d][n]
//   k2: attn_mfma -> AO f16 [b][n][C]
//   k3: gemm128<1>: proj + bias -> d_out f32

constexpr int B_ = 2, N_ = 2048, C_ = 1024, H_ = 16, D_ = 64;
constexpr int M_ = B_ * N_;   // 4096
constexpr int O3 = 3 * C_;    // 3072
constexpr int KVB = 64;
constexpr int NTILES = N_ / KVB;   // 32

typedef short bf16x8 __attribute__((ext_vector_type(8)));
typedef _Float16 half8 __attribute__((ext_vector_type(8)));
typedef _Float16 half4v __attribute__((ext_vector_type(4)));
typedef float f32x4  __attribute__((ext_vector_type(4)));
typedef float f32x16 __attribute__((ext_vector_type(16)));

__device__ __forceinline__ unsigned short f2bf(float f) {
    unsigned int u = __float_as_uint(f);
    unsigned int r = (u + 0x7FFFu + ((u >> 16) & 1u)) >> 16;
    return (unsigned short)r;
}

__device__ __forceinline__ void async16(const void* g, void* l) {
    __builtin_amdgcn_global_load_lds(
        (const __attribute__((address_space(1))) unsigned int*)g,
        (__attribute__((address_space(3))) unsigned int*)l, 16, 0, 0);
}

// ---------------- f32 -> f16 convert (x | w_qkv | w_proj) ----------------
constexpr size_t XN  = (size_t)M_ * C_;        // 4,194,304
constexpr size_t WQN = (size_t)O3 * C_;        // 3,145,728
constexpr size_t WPN = (size_t)C_ * C_;        // 1,048,576

__global__ __launch_bounds__(256)
void convert_f16(const float* __restrict__ x, const float* __restrict__ wq,
                 const float* __restrict__ wp, _Float16* __restrict__ dst)
{
    size_t i = ((size_t)blockIdx.x * 256 + threadIdx.x) * 8;
    const float* src;
    size_t off;
    if (i < XN)            { src = x;  off = i; }
    else if (i < XN + WQN) { src = wq; off = i - XN; }
    else                   { src = wp; off = i - XN - WQN; }
    float4 a = *(const float4*)(src + off);
    float4 b = *(const float4*)(src + off + 4);
    half8 h;
    h[0] = (_Float16)a.x; h[1] = (_Float16)a.y; h[2] = (_Float16)a.z; h[3] = (_Float16)a.w;
    h[4] = (_Float16)b.x; h[5] = (_Float16)b.y; h[6] = (_Float16)b.z; h[7] = (_Float16)b.w;
    *(half8*)(dst + i) = h;
}

// ---------------- f16 MFMA GEMM: 128x128 tile, BK=64, coalesced staging ----------
template<int MODE>
__global__ __launch_bounds__(256)
void gemm128(const _Float16* __restrict__ Ag, const _Float16* __restrict__ Bg,
             unsigned short* __restrict__ Qd, unsigned short* __restrict__ Kd,
             unsigned short* __restrict__ Vt,
             const float* __restrict__ bias, float* __restrict__ Out)
{
    __shared__ __align__(16) unsigned char Ab[2][16384];
    __shared__ __align__(16) unsigned char Bb[2][16384];

    const int t    = threadIdx.x;
    const int lane = t & 63;
    const int w    = t >> 6;
    const int g    = lane >> 4;
    const int c    = lane & 15;
    const int wm   = w >> 1, wn = w & 1;
    const int bm   = blockIdx.y * 128;
    const int bn   = blockIdx.x * 128;
    constexpr int K = C_;

    f32x4 acc[4][4];
    f32x4 zero = {0.f, 0.f, 0.f, 0.f};
    #pragma unroll
    for (int mi = 0; mi < 4; ++mi)
        #pragma unroll
        for (int ni = 0; ni < 4; ++ni) acc[mi][ni] = zero;

    auto stage = [&](int buf, int k0) {
        #pragma unroll
        for (int i = 0; i < 4; ++i) {
            int id  = t + 256 * i;        // 0..1023 = row*8 + p
            int row = id >> 3;
            int p   = id & 7;
            int gs  = p ^ (row & 7);      // pre-swizzled source granule
            async16(Ag + (size_t)(bm + row) * K + k0 + 8 * gs, &Ab[buf][id * 16]);
            async16(Bg + (size_t)(bn + row) * K + k0 + 8 * gs, &Bb[buf][id * 16]);
        }
    };

    stage(0, 0);
    __syncthreads();
    int cur = 0;

    for (int k0 = 0; k0 < K; k0 += 64) {
        if (k0 + 64 < K) stage(cur ^ 1, k0 + 64);   // prefetch next tile

        const unsigned char* Abase = Ab[cur];
        const unsigned char* Bbase = Bb[cur];
        #pragma unroll
        for (int s = 0; s < 2; ++s) {               // two k-slices of 32
            half8 af[4], bf[4];
            #pragma unroll
            for (int mi = 0; mi < 4; ++mi) {
                int row = wm * 64 + mi * 16 + c;
                af[mi] = *(const half8*)(Abase + (row * 8 + ((s * 4 + g) ^ (row & 7))) * 16);
            }
            #pragma unroll
            for (int ni = 0; ni < 4; ++ni) {
                int row = wn * 64 + ni * 16 + c;
                bf[ni] = *(const half8*)(Bbase + (row * 8 + ((s * 4 + g) ^ (row & 7))) * 16);
            }
            #pragma unroll
            for (int mi = 0; mi < 4; ++mi)
                #pragma unroll
                for (int ni = 0; ni < 4; ++ni)
                    acc[mi][ni] = __builtin_amdgcn_mfma_f32_16x16x32_f16(af[mi], bf[ni], acc[mi][ni], 0, 0, 0);
        }

        __syncthreads();   // drains this iter's prefetch + protects buffer swap
        cur ^= 1;
    }

    if constexpr (MODE == 0) {
        // scatter epilogue: o = which*1024 + h*64 + d (64-col wave region = one head)
        constexpr float QSCALE = 0.125f * 1.4426950408889634f;   // D^-0.5 * log2(e)
        const int o0 = bn + wn * 64;
        const int which = o0 >> 10;
        const int h  = (o0 & 1023) >> 6;
        const int m0 = bm + wm * 64;
        const int b  = m0 >> 11;
        const int n0 = m0 & 2047;
        const size_t bh = (size_t)b * H_ + h;
        if (which == 0) {
            unsigned short* base = Qd + (bh * N_) * D_;
            #pragma unroll
            for (int mi = 0; mi < 4; ++mi)
                #pragma unroll
                for (int ni = 0; ni < 4; ++ni)
                    #pragma unroll
                    for (int r = 0; r < 4; ++r)
                        base[(size_t)(n0 + mi * 16 + 4 * g + r) * D_ + ni * 16 + c] =
                            f2bf(acc[mi][ni][r] * QSCALE);
        } else if (which == 1) {
            unsigned short* base = Kd + (bh * N_) * D_;
            #pragma unroll
            for (int mi = 0; mi < 4; ++mi)
                #pragma unroll
                for (int ni = 0; ni < 4; ++ni)
                    #pragma unroll
                    for (int r = 0; r < 4; ++r)
                        base[(size_t)(n0 + mi * 16 + 4 * g + r) * D_ + ni * 16 + c] =
                            f2bf(acc[mi][ni][r]);
        } else {
            unsigned short* base = Vt + (bh * D_) * (size_t)N_;
            #pragma unroll
            for (int mi = 0; mi < 4; ++mi)
                #pragma unroll
                for (int ni = 0; ni < 4; ++ni) {
                    ushort4 v;
                    v.x = f2bf(acc[mi][ni][0]);
                    v.y = f2bf(acc[mi][ni][1]);
                    v.z = f2bf(acc[mi][ni][2]);
                    v.w = f2bf(acc[mi][ni][3]);
                    *(ushort4*)&base[(size_t)(ni * 16 + c) * N_ + n0 + mi * 16 + 4 * g] = v;
                }
        }
    } else {
        const int m0 = bm + wm * 64;
        const int o0 = bn + wn * 64;
        #pragma unroll
        for (int ni = 0; ni < 4; ++ni) {
            float bb = bias[o0 + ni * 16 + c];
            #pragma unroll
            for (int mi = 0; mi < 4; ++mi)
                #pragma unroll
                for (int r = 0; r < 4; ++r)
                    Out[(size_t)(m0 + mi * 16 + 4 * g + r) * C_ + o0 + ni * 16 + c] =
                        acc[mi][ni][r] + bb;
        }
    }
}

// ---------------- MFMA flash attention: 32x32x16, 4 waves x 32 q rows ----------
// 32x32x16 frags: A row=lane&31, k=8*(lane>>5)+e ; B col=lane&31, same k ;
// C/D col=lane&31, row=(reg&3)+8*(reg>>2)+4*(lane>>5)  [m74/m101].
// QK: S^T[key][q] = mfma(K_frag, Q_frag), 2 key-blocks x 4 d-slices.
// P redistribution: lane holds P[keys 8m+4h+i][q]; pack quads -> pkd[kb][m][j];
// v_permlane32_swap_b32(pkd[kb][2u][j], pkd[kb][2u+1][j]) yields quadA/quadB of
// PV B-frag pb[s=2kb+u] for BOTH h-halves (HK T12 pattern, zero selects).
// PV: out^T[d][q] = mfma(Vt_frag, pb[s]), 2 d-blocks x 4 key-slices.
__global__ __launch_bounds__(256, 2)
void attn_mfma(const unsigned short* __restrict__ Qd, const unsigned short* __restrict__ Kd,
               const unsigned short* __restrict__ Vt, _Float16* __restrict__ AO)
{
    __shared__ __align__(16) unsigned char KsB[2][8192];   // K tile  [key(64)][d(64)] bf16, swz
    __shared__ __align__(16) unsigned char VtB[2][8192];   // V^T tile [d(64)][key(64)] bf16, swz

    const int t    = threadIdx.x;
    const int lane = t & 63;
    const int w    = t >> 6;                 // 0..3
    const int h    = lane >> 5;              // 0..1
    const int q31  = lane & 31;
    const int qsw  = q31 & 7;

    // bijective XCD swizzle: 512 blocks, 64 works/XCD
    int flat = blockIdx.x;
    int work = (flat & 7) * 64 + (flat >> 3);
    const int bh = work >> 4;               // 0..31
    const int qt = work & 15;               // 0..15
    const int b  = bh >> 4, hh = bh & 15;
    const int q0 = qt * 128;

    const unsigned short* Kp = Kd + (size_t)bh * N_ * D_;
    const unsigned short* Vp = Vt + (size_t)bh * D_ * N_;

    // Q B-fragments: q = q0 + w*32 + q31, d = 16s + 8h + e
    const unsigned short* qp = Qd + ((size_t)bh * N_ + q0 + w * 32 + q31) * D_;
    bf16x8 qf[4];
    #pragma unroll
    for (int s = 0; s < 4; ++s)
        qf[s] = *(const bf16x8*)(qp + 16 * s + 8 * h);

    // staging addresses
    const int rk = t >> 3, pk = t & 7;       // row 0..31, granule
    const unsigned char* kSrc = (const unsigned char*)Kp + rk * 128 + ((pk ^ (rk & 7)) << 4);
    const unsigned char* vSrc = (const unsigned char*)Vp + (size_t)rk * (N_ * 2) + ((pk ^ (rk & 7)) << 4);
    unsigned char* kDstA = KsB[0] + t * 16;
    unsigned char* kDstB = KsB[1] + t * 16;
    unsigned char* vDstA = VtB[0] + t * 16;
    unsigned char* vDstB = VtB[1] + t * 16;

    float m_run = -1e30f, l_run = 0.f;
    f32x16 oc0 = 0.f, oc1 = 0.f;

    auto stage = [&](unsigned char* kD, unsigned char* vD, int kt) {
        async16(kSrc + (size_t)kt * 8192, kD);
        async16(kSrc + (size_t)kt * 8192 + 4096, kD + 4096);           // rows 32..63 (same swizzle)
        async16(vSrc + (size_t)kt * 128, vD);
        async16(vSrc + 32 * (size_t)(N_ * 2) + (size_t)kt * 128, vD + 4096);
    };

    stage(kDstA, vDstA, 0);
    __syncthreads();

    auto tile_body = [&](const unsigned char* kbase, const unsigned char* vbase,
                         unsigned char* kDstN, unsigned char* vDstN, int ktNext) {
        if (ktNext < NTILES) stage(kDstN, vDstN, ktNext);

        // ---- S^T = K * Q^T : 2 key-blocks x 4 d-slices ----
        f32x16 st0 = 0.f, st1 = 0.f;
        const unsigned char* krow0 = kbase + q31 * 128;
        const unsigned char* krow1 = kbase + (32 + q31) * 128;
        __builtin_amdgcn_s_setprio(1);
        #pragma unroll
        for (int s = 0; s < 4; ++s) {
            int go = ((2 * s + h) ^ qsw) << 4;
            bf16x8 a0 = *(const bf16x8*)(krow0 + go);
            bf16x8 a1 = *(const bf16x8*)(krow1 + go);
            st0 = __builtin_amdgcn_mfma_f32_32x32x16_bf16(a0, qf[s], st0, 0, 0, 0);
            st1 = __builtin_amdgcn_mfma_f32_32x32x16_bf16(a1, qf[s], st1, 0, 0, 0);
        }
        __builtin_amdgcn_s_setprio(0);

        // ---- column max: 16 vector max + tree + 1 cross-lane (xor 32) ----
        f32x16 mm;
        #pragma unroll
        for (int r = 0; r < 16; ++r) mm[r] = fmaxf(st0[r], st1[r]);
        float a0 = fmaxf(fmaxf(mm[0], mm[1]), mm[2]);
        float a1 = fmaxf(fmaxf(mm[3], mm[4]), mm[5]);
        float a2 = fmaxf(fmaxf(mm[6], mm[7]), mm[8]);
        float a3 = fmaxf(fmaxf(mm[9], mm[10]), mm[11]);
        float a4 = fmaxf(fmaxf(mm[12], mm[13]), mm[14]);
        float mx = fmaxf(fmaxf(fmaxf(a0, a1), fmaxf(a2, a3)), fmaxf(a4, mm[15]));
        mx = fmaxf(mx, __shfl_xor(mx, 32));

        // ---- defer-max (THR = 8 in log2 domain) ----
        const bool defer = __all(mx <= m_run + 8.f);
        if (!defer) {
            const float nm = fmaxf(m_run, mx);
            const float corr = exp2f(m_run - nm);
            m_run = nm;
            oc0 *= corr;
            oc1 *= corr;
            l_run *= corr;
        }
        #pragma unroll
        for (int r = 0; r < 16; ++r) {
            st0[r] = exp2f(st0[r] - m_run);
            st1[r] = exp2f(st1[r] - m_run);
        }

        // ---- denominator: vector sum + 1 cross-lane ----
        f32x16 sv = st0 + st1;
        float ts = ((sv[0] + sv[1]) + (sv[2] + sv[3])) + ((sv[4] + sv[5]) + (sv[6] + sv[7]))
                 + ((sv[8] + sv[9]) + (sv[10] + sv[11])) + ((sv[12] + sv[13]) + (sv[14] + sv[15]));
        ts += __shfl_xor(ts, 32);
        l_run += ts;

        // ---- pack P quads -> dwords (truncate to bf16) ----
        unsigned int pkd[2][4][2];
        #pragma unroll
        for (int m = 0; m < 4; ++m)
            #pragma unroll
            for (int j = 0; j < 2; ++j) {
                pkd[0][m][j] = __byte_perm(__float_as_uint(st0[4*m + 2*j]),
                                           __float_as_uint(st0[4*m + 2*j + 1]), 0x7632);
                pkd[1][m][j] = __byte_perm(__float_as_uint(st1[4*m + 2*j]),
                                           __float_as_uint(st1[4*m + 2*j + 1]), 0x7632);
            }

        // ---- permlane32_swap: (pk[2u], pk[2u+1]) -> (quadA, quadB) of pb[s=2kb+u] ----
        #pragma unroll
        for (int kb = 0; kb < 2; ++kb)
            #pragma unroll
            for (int u = 0; u < 2; ++u)
                #pragma unroll
                for (int j = 0; j < 2; ++j)
                    asm("v_permlane32_swap_b32 %0, %1"
                        : "+v"(pkd[kb][2*u][j]), "+v"(pkd[kb][2*u+1][j]));

        bf16x8 pb[4];
        #pragma unroll
        for (int s = 0; s < 4; ++s) {
            const int kb = s >> 1, u = s & 1;
            union { unsigned int d[4]; bf16x8 v; } uu;
            uu.d[0] = pkd[kb][2*u][0];
            uu.d[1] = pkd[kb][2*u][1];
            uu.d[2] = pkd[kb][2*u+1][0];
            uu.d[3] = pkd[kb][2*u+1][1];
            pb[s] = uu.v;
        }

        // ---- out^T += V^T * P : 2 d-blocks x 4 key-slices ----
        const unsigned char* vrow0 = vbase + q31 * 128;
        const unsigned char* vrow1 = vbase + (32 + q31) * 128;
        __builtin_amdgcn_s_setprio(1);
        #pragma unroll
        for (int s = 0; s < 4; ++s) {
            int go = ((2 * s + h) ^ qsw) << 4;
            bf16x8 va0 = *(const bf16x8*)(vrow0 + go);
            bf16x8 va1 = *(const bf16x8*)(vrow1 + go);
            oc0 = __builtin_amdgcn_mfma_f32_32x32x16_bf16(va0, pb[s], oc0, 0, 0, 0);
            oc1 = __builtin_amdgcn_mfma_f32_32x32x16_bf16(va1, pb[s], oc1, 0, 0, 0);
        }
        __builtin_amdgcn_s_setprio(0);

        __syncthreads();   // drains vmcnt (stage done) + protects buffer swap
    };

    #pragma unroll 1
    for (int kt = 0; kt < NTILES; kt += 2) {
        tile_body(KsB[0], VtB[0], kDstB, vDstB, kt + 1);
        tile_body(KsB[1], VtB[1], kDstA, vDstA, kt + 2);
    }

    // ---- epilogue: normalize, write AO f16 [b][q][hh*64 + d], d = 32db+8m+4h+i ----
    float inv = 1.0f / l_run;
    const int q = q0 + w * 32 + q31;
    _Float16* aop = AO + ((size_t)b * N_ + q) * C_ + hh * D_;
    #pragma unroll
    for (int m = 0; m < 4; ++m) {
        half4v o0, o1;
        #pragma unroll
        for (int i = 0; i < 4; ++i) {
            o0[i] = (_Float16)(oc0[4*m + i] * inv);
            o1[i] = (_Float16)(oc1[4*m + i] * inv);
        }
        *(half4v*)(aop + 8 * m + 4 * h) = o0;
        *(half4v*)(aop + 32 + 8 * m + 4 * h) = o1;
    }
}

extern "C" void kernel_launch(void* const* d_in, const int* in_sizes, int n_in,
                              void* d_out, int out_size, void* d_ws, size_t ws_size,
                              hipStream_t stream) {
    const float* x      = (const float*)d_in[0];
    const float* w_qkv  = (const float*)d_in[1];
    const float* w_proj = (const float*)d_in[2];
    const float* b_proj = (const float*)d_in[3];
    float* out = (float*)d_out;

    const size_t hd = (size_t)B_ * H_ * N_ * D_;   // 4,194,304 elems
    unsigned short* Qd = (unsigned short*)d_ws;
    unsigned short* Kd = Qd + hd;
    unsigned short* Vt = Kd + hd;
    _Float16* AO  = (_Float16*)(Vt + hd);          // [B,N,C] f16
    _Float16* x16 = AO + hd;                       // [4096][1024]
    _Float16* wq16 = x16 + XN;                     // [3072][1024]
    _Float16* wp16 = wq16 + WQN;                   // [1024][1024]

    convert_f16<<<4096, 256, 0, stream>>>(x, w_qkv, w_proj, x16);
    gemm128<0><<<dim3(O3 / 128, M_ / 128), 256, 0, stream>>>(
        x16, wq16, Qd, Kd, Vt, nullptr, nullptr);
    attn_mfma<<<dim3(512), 256, 0, stream>>>(Qd, Kd, Vt, AO);
    gemm128<1><<<dim3(C_ / 128, M_ / 128), 256, 0, stream>>>(
        AO, wp16, nullptr, nullptr, nullptr, b_proj, out);
}

// Round 11
// 123.979 us; speedup vs baseline: 1.1305x; 1.1294x over previous
//
#include <hip/hip_runtime.h>

// CustomAttention: x[2,2048,1024] f32, w_qkv[3072,1024], w_proj[1024,1024], b_proj[1024]
// Round 11: fast exp. exp2f lowers to an accurate multi-instr sequence (no fast-math);
//           replaced with raw v_exp_f32 (1 ulp — far above bf16-pack precision).
//           Hoisted per-tile granule offsets/row bases. Structure = round 10.
//   k0: convert_f16: x, w_qkv, w_proj f32 -> f16
//   k1: gemm128<0>: qkv -> Qd bf16 (scaled 0.125*log2e), Kd bf16, Vt bf16 [bh][d][n]
//   k2: attn_mfma (32x32x16, 4 waves x 32 q, in-reg P via permlane32_swap) -> AO f16
//   k3: gemm128<1>: proj + bias -> d_out f32

constexpr int B_ = 2, N_ = 2048, C_ = 1024, H_ = 16, D_ = 64;
constexpr int M_ = B_ * N_;   // 4096
constexpr int O3 = 3 * C_;    // 3072
constexpr int KVB = 64;
constexpr int NTILES = N_ / KVB;   // 32

typedef short bf16x8 __attribute__((ext_vector_type(8)));
typedef _Float16 half8 __attribute__((ext_vector_type(8)));
typedef _Float16 half4v __attribute__((ext_vector_type(4)));
typedef float f32x4  __attribute__((ext_vector_type(4)));
typedef float f32x16 __attribute__((ext_vector_type(16)));

__device__ __forceinline__ unsigned short f2bf(float f) {
    unsigned int u = __float_as_uint(f);
    unsigned int r = (u + 0x7FFFu + ((u >> 16) & 1u)) >> 16;
    return (unsigned short)r;
}

__device__ __forceinline__ float fexp2(float x) {
    float r;
    asm("v_exp_f32 %0, %1" : "=v"(r) : "v"(x));
    return r;
}

__device__ __forceinline__ void async16(const void* g, void* l) {
    __builtin_amdgcn_global_load_lds(
        (const __attribute__((address_space(1))) unsigned int*)g,
        (__attribute__((address_space(3))) unsigned int*)l, 16, 0, 0);
}

// ---------------- f32 -> f16 convert (x | w_qkv | w_proj) ----------------
constexpr size_t XN  = (size_t)M_ * C_;        // 4,194,304
constexpr size_t WQN = (size_t)O3 * C_;        // 3,145,728
constexpr size_t WPN = (size_t)C_ * C_;        // 1,048,576

__global__ __launch_bounds__(256)
void convert_f16(const float* __restrict__ x, const float* __restrict__ wq,
                 const float* __restrict__ wp, _Float16* __restrict__ dst)
{
    size_t i = ((size_t)blockIdx.x * 256 + threadIdx.x) * 8;
    const float* src;
    size_t off;
    if (i < XN)            { src = x;  off = i; }
    else if (i < XN + WQN) { src = wq; off = i - XN; }
    else                   { src = wp; off = i - XN - WQN; }
    float4 a = *(const float4*)(src + off);
    float4 b = *(const float4*)(src + off + 4);
    half8 h;
    h[0] = (_Float16)a.x; h[1] = (_Float16)a.y; h[2] = (_Float16)a.z; h[3] = (_Float16)a.w;
    h[4] = (_Float16)b.x; h[5] = (_Float16)b.y; h[6] = (_Float16)b.z; h[7] = (_Float16)b.w;
    *(half8*)(dst + i) = h;
}

// ---------------- f16 MFMA GEMM: 128x128 tile, BK=64, coalesced staging ----------
template<int MODE>
__global__ __launch_bounds__(256)
void gemm128(const _Float16* __restrict__ Ag, const _Float16* __restrict__ Bg,
             unsigned short* __restrict__ Qd, unsigned short* __restrict__ Kd,
             unsigned short* __restrict__ Vt,
             const float* __restrict__ bias, float* __restrict__ Out)
{
    __shared__ __align__(16) unsigned char Ab[2][16384];
    __shared__ __align__(16) unsigned char Bb[2][16384];

    const int t    = threadIdx.x;
    const int lane = t & 63;
    const int w    = t >> 6;
    const int g    = lane >> 4;
    const int c    = lane & 15;
    const int wm   = w >> 1, wn = w & 1;
    const int bm   = blockIdx.y * 128;
    const int bn   = blockIdx.x * 128;
    constexpr int K = C_;

    f32x4 acc[4][4];
    f32x4 zero = {0.f, 0.f, 0.f, 0.f};
    #pragma unroll
    for (int mi = 0; mi < 4; ++mi)
        #pragma unroll
        for (int ni = 0; ni < 4; ++ni) acc[mi][ni] = zero;

    auto stage = [&](int buf, int k0) {
        #pragma unroll
        for (int i = 0; i < 4; ++i) {
            int id  = t + 256 * i;        // 0..1023 = row*8 + p
            int row = id >> 3;
            int p   = id & 7;
            int gs  = p ^ (row & 7);      // pre-swizzled source granule
            async16(Ag + (size_t)(bm + row) * K + k0 + 8 * gs, &Ab[buf][id * 16]);
            async16(Bg + (size_t)(bn + row) * K + k0 + 8 * gs, &Bb[buf][id * 16]);
        }
    };

    stage(0, 0);
    __syncthreads();
    int cur = 0;

    for (int k0 = 0; k0 < K; k0 += 64) {
        if (k0 + 64 < K) stage(cur ^ 1, k0 + 64);   // prefetch next tile

        const unsigned char* Abase = Ab[cur];
        const unsigned char* Bbase = Bb[cur];
        #pragma unroll
        for (int s = 0; s < 2; ++s) {               // two k-slices of 32
            half8 af[4], bf[4];
            #pragma unroll
            for (int mi = 0; mi < 4; ++mi) {
                int row = wm * 64 + mi * 16 + c;
                af[mi] = *(const half8*)(Abase + (row * 8 + ((s * 4 + g) ^ (row & 7))) * 16);
            }
            #pragma unroll
            for (int ni = 0; ni < 4; ++ni) {
                int row = wn * 64 + ni * 16 + c;
                bf[ni] = *(const half8*)(Bbase + (row * 8 + ((s * 4 + g) ^ (row & 7))) * 16);
            }
            #pragma unroll
            for (int mi = 0; mi < 4; ++mi)
                #pragma unroll
                for (int ni = 0; ni < 4; ++ni)
                    acc[mi][ni] = __builtin_amdgcn_mfma_f32_16x16x32_f16(af[mi], bf[ni], acc[mi][ni], 0, 0, 0);
        }

        __syncthreads();   // drains this iter's prefetch + protects buffer swap
        cur ^= 1;
    }

    if constexpr (MODE == 0) {
        // scatter epilogue: o = which*1024 + h*64 + d (64-col wave region = one head)
        constexpr float QSCALE = 0.125f * 1.4426950408889634f;   // D^-0.5 * log2(e)
        const int o0 = bn + wn * 64;
        const int which = o0 >> 10;
        const int h  = (o0 & 1023) >> 6;
        const int m0 = bm + wm * 64;
        const int b  = m0 >> 11;
        const int n0 = m0 & 2047;
        const size_t bh = (size_t)b * H_ + h;
        if (which == 0) {
            unsigned short* base = Qd + (bh * N_) * D_;
            #pragma unroll
            for (int mi = 0; mi < 4; ++mi)
                #pragma unroll
                for (int ni = 0; ni < 4; ++ni)
                    #pragma unroll
                    for (int r = 0; r < 4; ++r)
                        base[(size_t)(n0 + mi * 16 + 4 * g + r) * D_ + ni * 16 + c] =
                            f2bf(acc[mi][ni][r] * QSCALE);
        } else if (which == 1) {
            unsigned short* base = Kd + (bh * N_) * D_;
            #pragma unroll
            for (int mi = 0; mi < 4; ++mi)
                #pragma unroll
                for (int ni = 0; ni < 4; ++ni)
                    #pragma unroll
                    for (int r = 0; r < 4; ++r)
                        base[(size_t)(n0 + mi * 16 + 4 * g + r) * D_ + ni * 16 + c] =
                            f2bf(acc[mi][ni][r]);
        } else {
            unsigned short* base = Vt + (bh * D_) * (size_t)N_;
            #pragma unroll
            for (int mi = 0; mi < 4; ++mi)
                #pragma unroll
                for (int ni = 0; ni < 4; ++ni) {
                    ushort4 v;
                    v.x = f2bf(acc[mi][ni][0]);
                    v.y = f2bf(acc[mi][ni][1]);
                    v.z = f2bf(acc[mi][ni][2]);
                    v.w = f2bf(acc[mi][ni][3]);
                    *(ushort4*)&base[(size_t)(ni * 16 + c) * N_ + n0 + mi * 16 + 4 * g] = v;
                }
        }
    } else {
        const int m0 = bm + wm * 64;
        const int o0 = bn + wn * 64;
        #pragma unroll
        for (int ni = 0; ni < 4; ++ni) {
            float bb = bias[o0 + ni * 16 + c];
            #pragma unroll
            for (int mi = 0; mi < 4; ++mi)
                #pragma unroll
                for (int r = 0; r < 4; ++r)
                    Out[(size_t)(m0 + mi * 16 + 4 * g + r) * C_ + o0 + ni * 16 + c] =
                        acc[mi][ni][r] + bb;
        }
    }
}

// ---------------- MFMA flash attention: 32x32x16, 4 waves x 32 q rows ----------
// 32x32x16 frags: A row=lane&31, k=8*(lane>>5)+e ; B col=lane&31, same k ;
// C/D col=lane&31, row=(reg&3)+8*(reg>>2)+4*(lane>>5)  [m74/m101].
__global__ __launch_bounds__(256, 2)
void attn_mfma(const unsigned short* __restrict__ Qd, const unsigned short* __restrict__ Kd,
               const unsigned short* __restrict__ Vt, _Float16* __restrict__ AO)
{
    __shared__ __align__(16) unsigned char KsB[2][8192];   // K tile  [key(64)][d(64)] bf16, swz
    __shared__ __align__(16) unsigned char VtB[2][8192];   // V^T tile [d(64)][key(64)] bf16, swz

    const int t    = threadIdx.x;
    const int lane = t & 63;
    const int w    = t >> 6;                 // 0..3
    const int h    = lane >> 5;              // 0..1
    const int q31  = lane & 31;
    const int qsw  = q31 & 7;

    // bijective XCD swizzle: 512 blocks, 64 works/XCD
    int flat = blockIdx.x;
    int work = (flat & 7) * 64 + (flat >> 3);
    const int bh = work >> 4;               // 0..31
    const int qt = work & 15;               // 0..15
    const int b  = bh >> 4, hh = bh & 15;
    const int q0 = qt * 128;

    const unsigned short* Kp = Kd + (size_t)bh * N_ * D_;
    const unsigned short* Vp = Vt + (size_t)bh * D_ * N_;

    // Q B-fragments: q = q0 + w*32 + q31, d = 16s + 8h + e
    const unsigned short* qp = Qd + ((size_t)bh * N_ + q0 + w * 32 + q31) * D_;
    bf16x8 qf[4];
    #pragma unroll
    for (int s = 0; s < 4; ++s)
        qf[s] = *(const bf16x8*)(qp + 16 * s + 8 * h);

    // hoisted per-thread constants
    int go[4];
    #pragma unroll
    for (int s = 0; s < 4; ++s) go[s] = ((2 * s + h) ^ qsw) << 4;
    const int row0off = q31 * 128;
    const int row1off = (32 + q31) * 128;

    // staging addresses
    const int rk = t >> 3, pk = t & 7;       // row 0..31, granule
    const unsigned char* kSrc = (const unsigned char*)Kp + rk * 128 + ((pk ^ (rk & 7)) << 4);
    const unsigned char* vSrc = (const unsigned char*)Vp + (size_t)rk * (N_ * 2) + ((pk ^ (rk & 7)) << 4);
    unsigned char* kDstA = KsB[0] + t * 16;
    unsigned char* kDstB = KsB[1] + t * 16;
    unsigned char* vDstA = VtB[0] + t * 16;
    unsigned char* vDstB = VtB[1] + t * 16;

    float m_run = -1e30f, l_run = 0.f;
    f32x16 oc0 = 0.f, oc1 = 0.f;

    auto stage = [&](unsigned char* kD, unsigned char* vD, int kt) {
        async16(kSrc + (size_t)kt * 8192, kD);
        async16(kSrc + (size_t)kt * 8192 + 4096, kD + 4096);           // rows 32..63
        async16(vSrc + (size_t)kt * 128, vD);
        async16(vSrc + 32 * (size_t)(N_ * 2) + (size_t)kt * 128, vD + 4096);
    };

    stage(kDstA, vDstA, 0);
    __syncthreads();

    auto tile_body = [&](const unsigned char* kbase, const unsigned char* vbase,
                         unsigned char* kDstN, unsigned char* vDstN, int ktNext) {
        if (ktNext < NTILES) stage(kDstN, vDstN, ktNext);

        // ---- S^T = K * Q^T : 2 key-blocks x 4 d-slices ----
        f32x16 st0 = 0.f, st1 = 0.f;
        const unsigned char* krow0 = kbase + row0off;
        const unsigned char* krow1 = kbase + row1off;
        __builtin_amdgcn_s_setprio(1);
        #pragma unroll
        for (int s = 0; s < 4; ++s) {
            bf16x8 a0 = *(const bf16x8*)(krow0 + go[s]);
            bf16x8 a1 = *(const bf16x8*)(krow1 + go[s]);
            st0 = __builtin_amdgcn_mfma_f32_32x32x16_bf16(a0, qf[s], st0, 0, 0, 0);
            st1 = __builtin_amdgcn_mfma_f32_32x32x16_bf16(a1, qf[s], st1, 0, 0, 0);
        }
        __builtin_amdgcn_s_setprio(0);

        // ---- column max: vector max + max3 tree + 1 cross-lane (xor 32) ----
        f32x16 mm;
        #pragma unroll
        for (int r = 0; r < 16; ++r) mm[r] = fmaxf(st0[r], st1[r]);
        float a0 = fmaxf(fmaxf(mm[0], mm[1]), mm[2]);
        float a1 = fmaxf(fmaxf(mm[3], mm[4]), mm[5]);
        float a2 = fmaxf(fmaxf(mm[6], mm[7]), mm[8]);
        float a3 = fmaxf(fmaxf(mm[9], mm[10]), mm[11]);
        float a4 = fmaxf(fmaxf(mm[12], mm[13]), mm[14]);
        float mx = fmaxf(fmaxf(fmaxf(a0, a1), fmaxf(a2, a3)), fmaxf(a4, mm[15]));
        mx = fmaxf(mx, __shfl_xor(mx, 32));

        // ---- defer-max (THR = 8 in log2 domain) ----
        const bool defer = __all(mx <= m_run + 8.f);
        if (!defer) {
            const float nm = fmaxf(m_run, mx);
            const float corr = fexp2(m_run - nm);
            m_run = nm;
            oc0 *= corr;
            oc1 *= corr;
            l_run *= corr;
        }
        #pragma unroll
        for (int r = 0; r < 16; ++r) {
            st0[r] = fexp2(st0[r] - m_run);
            st1[r] = fexp2(st1[r] - m_run);
        }

        // ---- denominator: vector sum + 1 cross-lane ----
        f32x16 sv = st0 + st1;
        float ts = ((sv[0] + sv[1]) + (sv[2] + sv[3])) + ((sv[4] + sv[5]) + (sv[6] + sv[7]))
                 + ((sv[8] + sv[9]) + (sv[10] + sv[11])) + ((sv[12] + sv[13]) + (sv[14] + sv[15]));
        ts += __shfl_xor(ts, 32);
        l_run += ts;

        // ---- pack P quads -> dwords (truncate to bf16) ----
        unsigned int pkd[2][4][2];
        #pragma unroll
        for (int m = 0; m < 4; ++m)
            #pragma unroll
            for (int j = 0; j < 2; ++j) {
                pkd[0][m][j] = __byte_perm(__float_as_uint(st0[4*m + 2*j]),
                                           __float_as_uint(st0[4*m + 2*j + 1]), 0x7632);
                pkd[1][m][j] = __byte_perm(__float_as_uint(st1[4*m + 2*j]),
                                           __float_as_uint(st1[4*m + 2*j + 1]), 0x7632);
            }

        // ---- permlane32_swap: (pk[2u], pk[2u+1]) -> (quadA, quadB) of pb[s=2kb+u] ----
        #pragma unroll
        for (int kb = 0; kb < 2; ++kb)
            #pragma unroll
            for (int u = 0; u < 2; ++u)
                #pragma unroll
                for (int j = 0; j < 2; ++j)
                    asm("v_permlane32_swap_b32 %0, %1"
                        : "+v"(pkd[kb][2*u][j]), "+v"(pkd[kb][2*u+1][j]));

        bf16x8 pb[4];
        #pragma unroll
        for (int s = 0; s < 4; ++s) {
            const int kb = s >> 1, u = s & 1;
            union { unsigned int d[4]; bf16x8 v; } uu;
            uu.d[0] = pkd[kb][2*u][0];
            uu.d[1] = pkd[kb][2*u][1];
            uu.d[2] = pkd[kb][2*u+1][0];
            uu.d[3] = pkd[kb][2*u+1][1];
            pb[s] = uu.v;
        }

        // ---- out^T += V^T * P : 2 d-blocks x 4 key-slices ----
        const unsigned char* vrow0 = vbase + row0off;
        const unsigned char* vrow1 = vbase + row1off;
        __builtin_amdgcn_s_setprio(1);
        #pragma unroll
        for (int s = 0; s < 4; ++s) {
            bf16x8 va0 = *(const bf16x8*)(vrow0 + go[s]);
            bf16x8 va1 = *(const bf16x8*)(vrow1 + go[s]);
            oc0 = __builtin_amdgcn_mfma_f32_32x32x16_bf16(va0, pb[s], oc0, 0, 0, 0);
            oc1 = __builtin_amdgcn_mfma_f32_32x32x16_bf16(va1, pb[s], oc1, 0, 0, 0);
        }
        __builtin_amdgcn_s_setprio(0);

        __syncthreads();   // drains vmcnt (stage done) + protects buffer swap
    };

    #pragma unroll 1
    for (int kt = 0; kt < NTILES; kt += 2) {
        tile_body(KsB[0], VtB[0], kDstB, vDstB, kt + 1);
        tile_body(KsB[1], VtB[1], kDstA, vDstA, kt + 2);
    }

    // ---- epilogue: normalize, write AO f16 [b][q][hh*64 + d], d = 32db+8m+4h+i ----
    float inv = 1.0f / l_run;
    const int q = q0 + w * 32 + q31;
    _Float16* aop = AO + ((size_t)b * N_ + q) * C_ + hh * D_;
    #pragma unroll
    for (int m = 0; m < 4; ++m) {
        half4v o0, o1;
        #pragma unroll
        for (int i = 0; i < 4; ++i) {
            o0[i] = (_Float16)(oc0[4*m + i] * inv);
            o1[i] = (_Float16)(oc1[4*m + i] * inv);
        }
        *(half4v*)(aop + 8 * m + 4 * h) = o0;
        *(half4v*)(aop + 32 + 8 * m + 4 * h) = o1;
    }
}

extern "C" void kernel_launch(void* const* d_in, const int* in_sizes, int n_in,
                              void* d_out, int out_size, void* d_ws, size_t ws_size,
                              hipStream_t stream) {
    const float* x      = (const float*)d_in[0];
    const float* w_qkv  = (const float*)d_in[1];
    const float* w_proj = (const float*)d_in[2];
    const float* b_proj = (const float*)d_in[3];
    float* out = (float*)d_out;

    const size_t hd = (size_t)B_ * H_ * N_ * D_;   // 4,194,304 elems
    unsigned short* Qd = (unsigned short*)d_ws;
    unsigned short* Kd = Qd + hd;
    unsigned short* Vt = Kd + hd;
    _Float16* AO  = (_Float16*)(Vt + hd);          // [B,N,C] f16
    _Float16* x16 = AO + hd;                       // [4096][1024]
    _Float16* wq16 = x16 + XN;                     // [3072][1024]
    _Float16* wp16 = wq16 + WQN;                   // [1024][1024]

    convert_f16<<<4096, 256, 0, stream>>>(x, w_qkv, w_proj, x16);
    gemm128<0><<<dim3(O3 / 128, M_ / 128), 256, 0, stream>>>(
        x16, wq16, Qd, Kd, Vt, nullptr, nullptr);
    attn_mfma<<<dim3(512), 256, 0, stream>>>(Qd, Kd, Vt, AO);
    gemm128<1><<<dim3(C_ / 128, M_ / 128), 256, 0, stream>>>(
        AO, wp16, nullptr, nullptr, nullptr, b_proj, out);
}

// Round 12
// 120.979 us; speedup vs baseline: 1.1585x; 1.0248x over previous
//
#include <hip/hip_runtime.h>

// CustomAttention: x[2,2048,1024] f32, w_qkv[3072,1024], w_proj[1024,1024], b_proj[1024]
// Round 12: split-KV attention. 8 waves/block: wave-group 0 -> KV tiles 0..15,
//           group 1 -> tiles 16..31, same 128 q rows; per-group 32KB K/V dbuf
//           (64KB/block, 2 blocks/CU -> 16 waves/CU = 4/SIMD, 2x latency hiding).
//           Intra-block flash-combine through LDS (reuses K buffers). GEMMs as r7.
//   k0: convert_f16: x, w_qkv, w_proj f32 -> f16
//   k1: gemm128<0>: qkv -> Qd bf16 (scaled 0.125*log2e), Kd bf16, Vt bf16 [bh][d][n]
//   k2: attn_mfma (32x32x16, split-KV, in-reg P via permlane32_swap) -> AO f16
//   k3: gemm128<1>: proj + bias -> d_out f32

constexpr int B_ = 2, N_ = 2048, C_ = 1024, H_ = 16, D_ = 64;
constexpr int M_ = B_ * N_;   // 4096
constexpr int O3 = 3 * C_;    // 3072
constexpr int KVB = 64;
constexpr int NTILES = N_ / KVB;   // 32

typedef short bf16x8 __attribute__((ext_vector_type(8)));
typedef _Float16 half8 __attribute__((ext_vector_type(8)));
typedef _Float16 half4v __attribute__((ext_vector_type(4)));
typedef float f32x4  __attribute__((ext_vector_type(4)));
typedef float f32x16 __attribute__((ext_vector_type(16)));

__device__ __forceinline__ unsigned short f2bf(float f) {
    unsigned int u = __float_as_uint(f);
    unsigned int r = (u + 0x7FFFu + ((u >> 16) & 1u)) >> 16;
    return (unsigned short)r;
}

__device__ __forceinline__ float fexp2(float x) {
    float r;
    asm("v_exp_f32 %0, %1" : "=v"(r) : "v"(x));
    return r;
}

__device__ __forceinline__ void async16(const void* g, void* l) {
    __builtin_amdgcn_global_load_lds(
        (const __attribute__((address_space(1))) unsigned int*)g,
        (__attribute__((address_space(3))) unsigned int*)l, 16, 0, 0);
}

// ---------------- f32 -> f16 convert (x | w_qkv | w_proj) ----------------
constexpr size_t XN  = (size_t)M_ * C_;        // 4,194,304
constexpr size_t WQN = (size_t)O3 * C_;        // 3,145,728
constexpr size_t WPN = (size_t)C_ * C_;        // 1,048,576

__global__ __launch_bounds__(256)
void convert_f16(const float* __restrict__ x, const float* __restrict__ wq,
                 const float* __restrict__ wp, _Float16* __restrict__ dst)
{
    size_t i = ((size_t)blockIdx.x * 256 + threadIdx.x) * 8;
    const float* src;
    size_t off;
    if (i < XN)            { src = x;  off = i; }
    else if (i < XN + WQN) { src = wq; off = i - XN; }
    else                   { src = wp; off = i - XN - WQN; }
    float4 a = *(const float4*)(src + off);
    float4 b = *(const float4*)(src + off + 4);
    half8 h;
    h[0] = (_Float16)a.x; h[1] = (_Float16)a.y; h[2] = (_Float16)a.z; h[3] = (_Float16)a.w;
    h[4] = (_Float16)b.x; h[5] = (_Float16)b.y; h[6] = (_Float16)b.z; h[7] = (_Float16)b.w;
    *(half8*)(dst + i) = h;
}

// ---------------- f16 MFMA GEMM: 128x128 tile, BK=64, coalesced staging ----------
template<int MODE>
__global__ __launch_bounds__(256)
void gemm128(const _Float16* __restrict__ Ag, const _Float16* __restrict__ Bg,
             unsigned short* __restrict__ Qd, unsigned short* __restrict__ Kd,
             unsigned short* __restrict__ Vt,
             const float* __restrict__ bias, float* __restrict__ Out)
{
    __shared__ __align__(16) unsigned char Ab[2][16384];
    __shared__ __align__(16) unsigned char Bb[2][16384];

    const int t    = threadIdx.x;
    const int lane = t & 63;
    const int w    = t >> 6;
    const int g    = lane >> 4;
    const int c    = lane & 15;
    const int wm   = w >> 1, wn = w & 1;
    const int bm   = blockIdx.y * 128;
    const int bn   = blockIdx.x * 128;
    constexpr int K = C_;

    f32x4 acc[4][4];
    f32x4 zero = {0.f, 0.f, 0.f, 0.f};
    #pragma unroll
    for (int mi = 0; mi < 4; ++mi)
        #pragma unroll
        for (int ni = 0; ni < 4; ++ni) acc[mi][ni] = zero;

    auto stage = [&](int buf, int k0) {
        #pragma unroll
        for (int i = 0; i < 4; ++i) {
            int id  = t + 256 * i;        // 0..1023 = row*8 + p
            int row = id >> 3;
            int p   = id & 7;
            int gs  = p ^ (row & 7);      // pre-swizzled source granule
            async16(Ag + (size_t)(bm + row) * K + k0 + 8 * gs, &Ab[buf][id * 16]);
            async16(Bg + (size_t)(bn + row) * K + k0 + 8 * gs, &Bb[buf][id * 16]);
        }
    };

    stage(0, 0);
    __syncthreads();
    int cur = 0;

    for (int k0 = 0; k0 < K; k0 += 64) {
        if (k0 + 64 < K) stage(cur ^ 1, k0 + 64);   // prefetch next tile

        const unsigned char* Abase = Ab[cur];
        const unsigned char* Bbase = Bb[cur];
        #pragma unroll
        for (int s = 0; s < 2; ++s) {               // two k-slices of 32
            half8 af[4], bf[4];
            #pragma unroll
            for (int mi = 0; mi < 4; ++mi) {
                int row = wm * 64 + mi * 16 + c;
                af[mi] = *(const half8*)(Abase + (row * 8 + ((s * 4 + g) ^ (row & 7))) * 16);
            }
            #pragma unroll
            for (int ni = 0; ni < 4; ++ni) {
                int row = wn * 64 + ni * 16 + c;
                bf[ni] = *(const half8*)(Bbase + (row * 8 + ((s * 4 + g) ^ (row & 7))) * 16);
            }
            #pragma unroll
            for (int mi = 0; mi < 4; ++mi)
                #pragma unroll
                for (int ni = 0; ni < 4; ++ni)
                    acc[mi][ni] = __builtin_amdgcn_mfma_f32_16x16x32_f16(af[mi], bf[ni], acc[mi][ni], 0, 0, 0);
        }

        __syncthreads();   // drains this iter's prefetch + protects buffer swap
        cur ^= 1;
    }

    if constexpr (MODE == 0) {
        // scatter epilogue: o = which*1024 + h*64 + d (64-col wave region = one head)
        constexpr float QSCALE = 0.125f * 1.4426950408889634f;   // D^-0.5 * log2(e)
        const int o0 = bn + wn * 64;
        const int which = o0 >> 10;
        const int h  = (o0 & 1023) >> 6;
        const int m0 = bm + wm * 64;
        const int b  = m0 >> 11;
        const int n0 = m0 & 2047;
        const size_t bh = (size_t)b * H_ + h;
        if (which == 0) {
            unsigned short* base = Qd + (bh * N_) * D_;
            #pragma unroll
            for (int mi = 0; mi < 4; ++mi)
                #pragma unroll
                for (int ni = 0; ni < 4; ++ni)
                    #pragma unroll
                    for (int r = 0; r < 4; ++r)
                        base[(size_t)(n0 + mi * 16 + 4 * g + r) * D_ + ni * 16 + c] =
                            f2bf(acc[mi][ni][r] * QSCALE);
        } else if (which == 1) {
            unsigned short* base = Kd + (bh * N_) * D_;
            #pragma unroll
            for (int mi = 0; mi < 4; ++mi)
                #pragma unroll
                for (int ni = 0; ni < 4; ++ni)
                    #pragma unroll
                    for (int r = 0; r < 4; ++r)
                        base[(size_t)(n0 + mi * 16 + 4 * g + r) * D_ + ni * 16 + c] =
                            f2bf(acc[mi][ni][r]);
        } else {
            unsigned short* base = Vt + (bh * D_) * (size_t)N_;
            #pragma unroll
            for (int mi = 0; mi < 4; ++mi)
                #pragma unroll
                for (int ni = 0; ni < 4; ++ni) {
                    ushort4 v;
                    v.x = f2bf(acc[mi][ni][0]);
                    v.y = f2bf(acc[mi][ni][1]);
                    v.z = f2bf(acc[mi][ni][2]);
                    v.w = f2bf(acc[mi][ni][3]);
                    *(ushort4*)&base[(size_t)(ni * 16 + c) * N_ + n0 + mi * 16 + 4 * g] = v;
                }
        }
    } else {
        const int m0 = bm + wm * 64;
        const int o0 = bn + wn * 64;
        #pragma unroll
        for (int ni = 0; ni < 4; ++ni) {
            float bb = bias[o0 + ni * 16 + c];
            #pragma unroll
            for (int mi = 0; mi < 4; ++mi)
                #pragma unroll
                for (int r = 0; r < 4; ++r)
                    Out[(size_t)(m0 + mi * 16 + 4 * g + r) * C_ + o0 + ni * 16 + c] =
                        acc[mi][ni][r] + bb;
        }
    }
}

// ---------------- MFMA flash attention: split-KV, 8 waves, 128 q / block ----------
// 32x32x16 frags: A row=lane&31, k=8*(lane>>5)+e ; B col=lane&31, same k ;
// C/D col=lane&31, row=(reg&3)+8*(reg>>2)+4*(lane>>5)  [m74/m101].
// Wave-group wg = w>>2 handles KV tiles [wg*16, wg*16+16); wl = w&3 picks q sub-tile.
// Final: group 1 stores {oc, m, l} to LDS (reusing Kbuf), group 0 flash-combines.
__global__ __launch_bounds__(512, 4)
void attn_mfma(const unsigned short* __restrict__ Qd, const unsigned short* __restrict__ Kd,
               const unsigned short* __restrict__ Vt, _Float16* __restrict__ AO)
{
    __shared__ __align__(16) unsigned char Kbuf[2][2][8192];  // [wg][buf] K tile, swz
    __shared__ __align__(16) unsigned char Vbuf[2][2][8192];  // [wg][buf] V^T tile, swz

    const int t    = threadIdx.x;
    const int lane = t & 63;
    const int w    = t >> 6;                 // 0..7
    const int wg   = w >> 2;                 // KV half
    const int wl   = w & 3;                  // q sub-tile
    const int tl   = t & 255;                // index within wave-group
    const int h    = lane >> 5;              // 0..1
    const int q31  = lane & 31;
    const int qsw  = q31 & 7;

    // bijective XCD swizzle: 512 blocks, 64 works/XCD
    int flat = blockIdx.x;
    int work = (flat & 7) * 64 + (flat >> 3);
    const int bh = work >> 4;               // 0..31
    const int qt = work & 15;               // 0..15
    const int b  = bh >> 4, hh = bh & 15;
    const int q0 = qt * 128;

    const unsigned short* Kp = Kd + (size_t)bh * N_ * D_;
    const unsigned short* Vp = Vt + (size_t)bh * D_ * N_;

    // Q B-fragments: q = q0 + wl*32 + q31, d = 16s + 8h + e
    const unsigned short* qp = Qd + ((size_t)bh * N_ + q0 + wl * 32 + q31) * D_;
    bf16x8 qf[4];
    #pragma unroll
    for (int s = 0; s < 4; ++s)
        qf[s] = *(const bf16x8*)(qp + 16 * s + 8 * h);

    // hoisted per-thread constants
    int go[4];
    #pragma unroll
    for (int s = 0; s < 4; ++s) go[s] = ((2 * s + h) ^ qsw) << 4;
    const int row0off = q31 * 128;
    const int row1off = (32 + q31) * 128;

    // staging addresses (per wave-group)
    const int rk = tl >> 3, pk = tl & 7;     // row 0..31, granule
    const unsigned char* kSrc = (const unsigned char*)Kp + rk * 128 + ((pk ^ (rk & 7)) << 4);
    const unsigned char* vSrc = (const unsigned char*)Vp + (size_t)rk * (N_ * 2) + ((pk ^ (rk & 7)) << 4);
    unsigned char* kDstA = Kbuf[wg][0] + tl * 16;
    unsigned char* kDstB = Kbuf[wg][1] + tl * 16;
    unsigned char* vDstA = Vbuf[wg][0] + tl * 16;
    unsigned char* vDstB = Vbuf[wg][1] + tl * 16;
    const unsigned char* kb0 = Kbuf[wg][0];
    const unsigned char* kb1 = Kbuf[wg][1];
    const unsigned char* vb0 = Vbuf[wg][0];
    const unsigned char* vb1 = Vbuf[wg][1];

    float m_run = -1e30f, l_run = 0.f;
    f32x16 oc0 = 0.f, oc1 = 0.f;

    auto stage = [&](unsigned char* kD, unsigned char* vD, int kt) {
        async16(kSrc + (size_t)kt * 8192, kD);
        async16(kSrc + (size_t)kt * 8192 + 4096, kD + 4096);           // rows 32..63
        async16(vSrc + (size_t)kt * 128, vD);
        async16(vSrc + 32 * (size_t)(N_ * 2) + (size_t)kt * 128, vD + 4096);
    };

    const int kt0 = wg * 16, ktEnd = kt0 + 16;
    stage(kDstA, vDstA, kt0);
    __syncthreads();

    auto tile_body = [&](const unsigned char* kbase, const unsigned char* vbase,
                         unsigned char* kDstN, unsigned char* vDstN, int ktNext) {
        if (ktNext < ktEnd) stage(kDstN, vDstN, ktNext);

        // ---- S^T = K * Q^T : 2 key-blocks x 4 d-slices ----
        f32x16 st0 = 0.f, st1 = 0.f;
        const unsigned char* krow0 = kbase + row0off;
        const unsigned char* krow1 = kbase + row1off;
        __builtin_amdgcn_s_setprio(1);
        #pragma unroll
        for (int s = 0; s < 4; ++s) {
            bf16x8 a0 = *(const bf16x8*)(krow0 + go[s]);
            bf16x8 a1 = *(const bf16x8*)(krow1 + go[s]);
            st0 = __builtin_amdgcn_mfma_f32_32x32x16_bf16(a0, qf[s], st0, 0, 0, 0);
            st1 = __builtin_amdgcn_mfma_f32_32x32x16_bf16(a1, qf[s], st1, 0, 0, 0);
        }
        __builtin_amdgcn_s_setprio(0);

        // ---- column max: vector max + tree + 1 cross-lane (xor 32) ----
        f32x16 mm;
        #pragma unroll
        for (int r = 0; r < 16; ++r) mm[r] = fmaxf(st0[r], st1[r]);
        float a0 = fmaxf(fmaxf(mm[0], mm[1]), mm[2]);
        float a1 = fmaxf(fmaxf(mm[3], mm[4]), mm[5]);
        float a2 = fmaxf(fmaxf(mm[6], mm[7]), mm[8]);
        float a3 = fmaxf(fmaxf(mm[9], mm[10]), mm[11]);
        float a4 = fmaxf(fmaxf(mm[12], mm[13]), mm[14]);
        float mx = fmaxf(fmaxf(fmaxf(a0, a1), fmaxf(a2, a3)), fmaxf(a4, mm[15]));
        mx = fmaxf(mx, __shfl_xor(mx, 32));

        // ---- defer-max (THR = 8 in log2 domain) ----
        const bool defer = __all(mx <= m_run + 8.f);
        if (!defer) {
            const float nm = fmaxf(m_run, mx);
            const float corr = fexp2(m_run - nm);
            m_run = nm;
            oc0 *= corr;
            oc1 *= corr;
            l_run *= corr;
        }
        #pragma unroll
        for (int r = 0; r < 16; ++r) {
            st0[r] = fexp2(st0[r] - m_run);
            st1[r] = fexp2(st1[r] - m_run);
        }

        // ---- denominator: vector sum + 1 cross-lane ----
        f32x16 sv = st0 + st1;
        float ts = ((sv[0] + sv[1]) + (sv[2] + sv[3])) + ((sv[4] + sv[5]) + (sv[6] + sv[7]))
                 + ((sv[8] + sv[9]) + (sv[10] + sv[11])) + ((sv[12] + sv[13]) + (sv[14] + sv[15]));
        ts += __shfl_xor(ts, 32);
        l_run += ts;

        // ---- pack P quads -> dwords (truncate to bf16) ----
        unsigned int pkd[2][4][2];
        #pragma unroll
        for (int m = 0; m < 4; ++m)
            #pragma unroll
            for (int j = 0; j < 2; ++j) {
                pkd[0][m][j] = __byte_perm(__float_as_uint(st0[4*m + 2*j]),
                                           __float_as_uint(st0[4*m + 2*j + 1]), 0x7632);
                pkd[1][m][j] = __byte_perm(__float_as_uint(st1[4*m + 2*j]),
                                           __float_as_uint(st1[4*m + 2*j + 1]), 0x7632);
            }

        // ---- permlane32_swap: (pk[2u], pk[2u+1]) -> (quadA, quadB) of pb[s=2kb+u] ----
        #pragma unroll
        for (int kb = 0; kb < 2; ++kb)
            #pragma unroll
            for (int u = 0; u < 2; ++u)
                #pragma unroll
                for (int j = 0; j < 2; ++j)
                    asm("v_permlane32_swap_b32 %0, %1"
                        : "+v"(pkd[kb][2*u][j]), "+v"(pkd[kb][2*u+1][j]));

        bf16x8 pb[4];
        #pragma unroll
        for (int s = 0; s < 4; ++s) {
            const int kb = s >> 1, u = s & 1;
            union { unsigned int d[4]; bf16x8 v; } uu;
            uu.d[0] = pkd[kb][2*u][0];
            uu.d[1] = pkd[kb][2*u][1];
            uu.d[2] = pkd[kb][2*u+1][0];
            uu.d[3] = pkd[kb][2*u+1][1];
            pb[s] = uu.v;
        }

        // ---- out^T += V^T * P : 2 d-blocks x 4 key-slices ----
        const unsigned char* vrow0 = vbase + row0off;
        const unsigned char* vrow1 = vbase + row1off;
        __builtin_amdgcn_s_setprio(1);
        #pragma unroll
        for (int s = 0; s < 4; ++s) {
            bf16x8 va0 = *(const bf16x8*)(vrow0 + go[s]);
            bf16x8 va1 = *(const bf16x8*)(vrow1 + go[s]);
            oc0 = __builtin_amdgcn_mfma_f32_32x32x16_bf16(va0, pb[s], oc0, 0, 0, 0);
            oc1 = __builtin_amdgcn_mfma_f32_32x32x16_bf16(va1, pb[s], oc1, 0, 0, 0);
        }
        __builtin_amdgcn_s_setprio(0);

        __syncthreads();   // drains vmcnt (stage done) + protects buffer swap
    };

    #pragma unroll 1
    for (int kt = kt0; kt < ktEnd; kt += 2) {
        tile_body(kb0, vb0, kDstB, vDstB, kt + 1);
        tile_body(kb1, vb1, kDstA, vDstA, kt + 2);
    }

    // ---- split-KV combine through LDS (reuse Kbuf; 256 slots x 40 f32) ----
    float* cb = (float*)&Kbuf[0][0][0];
    if (wg == 1) {
        float* s = cb + tl * 40;
        #pragma unroll
        for (int m = 0; m < 4; ++m) {
            f32x4 a, bq;
            #pragma unroll
            for (int i = 0; i < 4; ++i) { a[i] = oc0[4*m + i]; bq[i] = oc1[4*m + i]; }
            *(f32x4*)(s + 4 * m) = a;
            *(f32x4*)(s + 16 + 4 * m) = bq;
        }
        s[32] = m_run;
        s[33] = l_run;
    }
    __syncthreads();
    if (wg == 0) {
        const float* s = cb + tl * 40;
        float m1 = s[32], l1 = s[33];
        float mm = fmaxf(m_run, m1);
        float c0 = fexp2(m_run - mm);
        float c1 = fexp2(m1 - mm);
        float inv = 1.0f / (l_run * c0 + l1 * c1);
        const int q = q0 + wl * 32 + q31;
        _Float16* aop = AO + ((size_t)b * N_ + q) * C_ + hh * D_;
        #pragma unroll
        for (int m = 0; m < 4; ++m) {
            half4v o0, o1;
            #pragma unroll
            for (int i = 0; i < 4; ++i) {
                o0[i] = (_Float16)((oc0[4*m + i] * c0 + s[4*m + i] * c1) * inv);
                o1[i] = (_Float16)((oc1[4*m + i] * c0 + s[16 + 4*m + i] * c1) * inv);
            }
            *(half4v*)(aop + 8 * m + 4 * h) = o0;
            *(half4v*)(aop + 32 + 8 * m + 4 * h) = o1;
        }
    }
}

extern "C" void kernel_launch(void* const* d_in, const int* in_sizes, int n_in,
                              void* d_out, int out_size, void* d_ws, size_t ws_size,
                              hipStream_t stream) {
    const float* x      = (const float*)d_in[0];
    const float* w_qkv  = (const float*)d_in[1];
    const float* w_proj = (const float*)d_in[2];
    const float* b_proj = (const float*)d_in[3];
    float* out = (float*)d_out;

    const size_t hd = (size_t)B_ * H_ * N_ * D_;   // 4,194,304 elems
    unsigned short* Qd = (unsigned short*)d_ws;
    unsigned short* Kd = Qd + hd;
    unsigned short* Vt = Kd + hd;
    _Float16* AO  = (_Float16*)(Vt + hd);          // [B,N,C] f16
    _Float16* x16 = AO + hd;                       // [4096][1024]
    _Float16* wq16 = x16 + XN;                     // [3072][1024]
    _Float16* wp16 = wq16 + WQN;                   // [1024][1024]

    convert_f16<<<4096, 256, 0, stream>>>(x, w_qkv, w_proj, x16);
    gemm128<0><<<dim3(O3 / 128, M_ / 128), 256, 0, stream>>>(
        x16, wq16, Qd, Kd, Vt, nullptr, nullptr);
    attn_mfma<<<dim3(512), 512, 0, stream>>>(Qd, Kd, Vt, AO);
    gemm128<1><<<dim3(C_ / 128, M_ / 128), 256, 0, stream>>>(
        AO, wp16, nullptr, nullptr, nullptr, b_proj, out);
}

// Round 14
// 120.748 us; speedup vs baseline: 1.1607x; 1.0019x over previous
//
#include <hip/hip_runtime.h>

// CustomAttention: x[2,2048,1024] f32, w_qkv[3072,1024], w_proj[1024,1024], b_proj[1024]
// Round 14: revert r13's max-free softmax (FAILED). Attention = round 12 defer-max
//           structure exactly, but exp2 via __builtin_amdgcn_exp2f instead of raw
//           inline asm — raw asm hides the transcendental op from the compiler's
//           hazard handling (trans-op write -> dependent VALU read needs a wait
//           state); r13's schedule exposed stale reads. GEMMs unchanged (round 7).
//   k0: convert_f16: x, w_qkv, w_proj f32 -> f16
//   k1: gemm128<0>: qkv -> Qd bf16 (scaled 0.125*log2e), Kd bf16, Vt bf16 [bh][d][n]
//   k2: attn_mfma (32x32x16, split-KV, in-reg P via permlane32_swap) -> AO f16
//   k3: gemm128<1>: proj + bias -> d_out f32

constexpr int B_ = 2, N_ = 2048, C_ = 1024, H_ = 16, D_ = 64;
constexpr int M_ = B_ * N_;   // 4096
constexpr int O3 = 3 * C_;    // 3072
constexpr int KVB = 64;
constexpr int NTILES = N_ / KVB;   // 32

typedef short bf16x8 __attribute__((ext_vector_type(8)));
typedef _Float16 half8 __attribute__((ext_vector_type(8)));
typedef _Float16 half4v __attribute__((ext_vector_type(4)));
typedef float f32x4  __attribute__((ext_vector_type(4)));
typedef float f32x16 __attribute__((ext_vector_type(16)));

__device__ __forceinline__ unsigned short f2bf(float f) {
    unsigned int u = __float_as_uint(f);
    unsigned int r = (u + 0x7FFFu + ((u >> 16) & 1u)) >> 16;
    return (unsigned short)r;
}

__device__ __forceinline__ float fexp2(float x) {
    return __builtin_amdgcn_exp2f(x);   // v_exp_f32 with compiler-managed hazards
}

__device__ __forceinline__ void async16(const void* g, void* l) {
    __builtin_amdgcn_global_load_lds(
        (const __attribute__((address_space(1))) unsigned int*)g,
        (__attribute__((address_space(3))) unsigned int*)l, 16, 0, 0);
}

// ---------------- f32 -> f16 convert (x | w_qkv | w_proj) ----------------
constexpr size_t XN  = (size_t)M_ * C_;        // 4,194,304
constexpr size_t WQN = (size_t)O3 * C_;        // 3,145,728
constexpr size_t WPN = (size_t)C_ * C_;        // 1,048,576

__global__ __launch_bounds__(256)
void convert_f16(const float* __restrict__ x, const float* __restrict__ wq,
                 const float* __restrict__ wp, _Float16* __restrict__ dst)
{
    size_t i = ((size_t)blockIdx.x * 256 + threadIdx.x) * 8;
    const float* src;
    size_t off;
    if (i < XN)            { src = x;  off = i; }
    else if (i < XN + WQN) { src = wq; off = i - XN; }
    else                   { src = wp; off = i - XN - WQN; }
    float4 a = *(const float4*)(src + off);
    float4 b = *(const float4*)(src + off + 4);
    half8 h;
    h[0] = (_Float16)a.x; h[1] = (_Float16)a.y; h[2] = (_Float16)a.z; h[3] = (_Float16)a.w;
    h[4] = (_Float16)b.x; h[5] = (_Float16)b.y; h[6] = (_Float16)b.z; h[7] = (_Float16)b.w;
    *(half8*)(dst + i) = h;
}

// ---------------- f16 MFMA GEMM: 128x128 tile, BK=64, coalesced staging ----------
template<int MODE>
__global__ __launch_bounds__(256)
void gemm128(const _Float16* __restrict__ Ag, const _Float16* __restrict__ Bg,
             unsigned short* __restrict__ Qd, unsigned short* __restrict__ Kd,
             unsigned short* __restrict__ Vt,
             const float* __restrict__ bias, float* __restrict__ Out)
{
    __shared__ __align__(16) unsigned char Ab[2][16384];
    __shared__ __align__(16) unsigned char Bb[2][16384];

    const int t    = threadIdx.x;
    const int lane = t & 63;
    const int w    = t >> 6;
    const int g    = lane >> 4;
    const int c    = lane & 15;
    const int wm   = w >> 1, wn = w & 1;
    const int bm   = blockIdx.y * 128;
    const int bn   = blockIdx.x * 128;
    constexpr int K = C_;

    f32x4 acc[4][4];
    f32x4 zero = {0.f, 0.f, 0.f, 0.f};
    #pragma unroll
    for (int mi = 0; mi < 4; ++mi)
        #pragma unroll
        for (int ni = 0; ni < 4; ++ni) acc[mi][ni] = zero;

    auto stage = [&](int buf, int k0) {
        #pragma unroll
        for (int i = 0; i < 4; ++i) {
            int id  = t + 256 * i;        // 0..1023 = row*8 + p
            int row = id >> 3;
            int p   = id & 7;
            int gs  = p ^ (row & 7);      // pre-swizzled source granule
            async16(Ag + (size_t)(bm + row) * K + k0 + 8 * gs, &Ab[buf][id * 16]);
            async16(Bg + (size_t)(bn + row) * K + k0 + 8 * gs, &Bb[buf][id * 16]);
        }
    };

    stage(0, 0);
    __syncthreads();
    int cur = 0;

    for (int k0 = 0; k0 < K; k0 += 64) {
        if (k0 + 64 < K) stage(cur ^ 1, k0 + 64);   // prefetch next tile

        const unsigned char* Abase = Ab[cur];
        const unsigned char* Bbase = Bb[cur];
        #pragma unroll
        for (int s = 0; s < 2; ++s) {               // two k-slices of 32
            half8 af[4], bf[4];
            #pragma unroll
            for (int mi = 0; mi < 4; ++mi) {
                int row = wm * 64 + mi * 16 + c;
                af[mi] = *(const half8*)(Abase + (row * 8 + ((s * 4 + g) ^ (row & 7))) * 16);
            }
            #pragma unroll
            for (int ni = 0; ni < 4; ++ni) {
                int row = wn * 64 + ni * 16 + c;
                bf[ni] = *(const half8*)(Bbase + (row * 8 + ((s * 4 + g) ^ (row & 7))) * 16);
            }
            #pragma unroll
            for (int mi = 0; mi < 4; ++mi)
                #pragma unroll
                for (int ni = 0; ni < 4; ++ni)
                    acc[mi][ni] = __builtin_amdgcn_mfma_f32_16x16x32_f16(af[mi], bf[ni], acc[mi][ni], 0, 0, 0);
        }

        __syncthreads();   // drains this iter's prefetch + protects buffer swap
        cur ^= 1;
    }

    if constexpr (MODE == 0) {
        // scatter epilogue: o = which*1024 + h*64 + d (64-col wave region = one head)
        constexpr float QSCALE = 0.125f * 1.4426950408889634f;   // D^-0.5 * log2(e)
        const int o0 = bn + wn * 64;
        const int which = o0 >> 10;
        const int h  = (o0 & 1023) >> 6;
        const int m0 = bm + wm * 64;
        const int b  = m0 >> 11;
        const int n0 = m0 & 2047;
        const size_t bh = (size_t)b * H_ + h;
        if (which == 0) {
            unsigned short* base = Qd + (bh * N_) * D_;
            #pragma unroll
            for (int mi = 0; mi < 4; ++mi)
                #pragma unroll
                for (int ni = 0; ni < 4; ++ni)
                    #pragma unroll
                    for (int r = 0; r < 4; ++r)
                        base[(size_t)(n0 + mi * 16 + 4 * g + r) * D_ + ni * 16 + c] =
                            f2bf(acc[mi][ni][r] * QSCALE);
        } else if (which == 1) {
            unsigned short* base = Kd + (bh * N_) * D_;
            #pragma unroll
            for (int mi = 0; mi < 4; ++mi)
                #pragma unroll
                for (int ni = 0; ni < 4; ++ni)
                    #pragma unroll
                    for (int r = 0; r < 4; ++r)
                        base[(size_t)(n0 + mi * 16 + 4 * g + r) * D_ + ni * 16 + c] =
                            f2bf(acc[mi][ni][r]);
        } else {
            unsigned short* base = Vt + (bh * D_) * (size_t)N_;
            #pragma unroll
            for (int mi = 0; mi < 4; ++mi)
                #pragma unroll
                for (int ni = 0; ni < 4; ++ni) {
                    ushort4 v;
                    v.x = f2bf(acc[mi][ni][0]);
                    v.y = f2bf(acc[mi][ni][1]);
                    v.z = f2bf(acc[mi][ni][2]);
                    v.w = f2bf(acc[mi][ni][3]);
                    *(ushort4*)&base[(size_t)(ni * 16 + c) * N_ + n0 + mi * 16 + 4 * g] = v;
                }
        }
    } else {
        const int m0 = bm + wm * 64;
        const int o0 = bn + wn * 64;
        #pragma unroll
        for (int ni = 0; ni < 4; ++ni) {
            float bb = bias[o0 + ni * 16 + c];
            #pragma unroll
            for (int mi = 0; mi < 4; ++mi)
                #pragma unroll
                for (int r = 0; r < 4; ++r)
                    Out[(size_t)(m0 + mi * 16 + 4 * g + r) * C_ + o0 + ni * 16 + c] =
                        acc[mi][ni][r] + bb;
        }
    }
}

// ---------------- MFMA flash attention: split-KV, 8 waves, 128 q / block ----------
// 32x32x16 frags: A row=lane&31, k=8*(lane>>5)+e ; B col=lane&31, same k ;
// C/D col=lane&31, row=(reg&3)+8*(reg>>2)+4*(lane>>5)  [m74/m101].
// Wave-group wg = w>>2 handles KV tiles [wg*16, wg*16+16); wl = w&3 picks q sub-tile.
// Final: group 1 stores {oc, m, l} to LDS (reusing Kbuf), group 0 flash-combines.
__global__ __launch_bounds__(512, 4)
void attn_mfma(const unsigned short* __restrict__ Qd, const unsigned short* __restrict__ Kd,
               const unsigned short* __restrict__ Vt, _Float16* __restrict__ AO)
{
    __shared__ __align__(16) unsigned char Kbuf[2][2][8192];  // [wg][buf] K tile, swz
    __shared__ __align__(16) unsigned char Vbuf[2][2][8192];  // [wg][buf] V^T tile, swz

    const int t    = threadIdx.x;
    const int lane = t & 63;
    const int w    = t >> 6;                 // 0..7
    const int wg   = w >> 2;                 // KV half
    const int wl   = w & 3;                  // q sub-tile
    const int tl   = t & 255;                // index within wave-group
    const int h    = lane >> 5;              // 0..1
    const int q31  = lane & 31;
    const int qsw  = q31 & 7;

    // bijective XCD swizzle: 512 blocks, 64 works/XCD
    int flat = blockIdx.x;
    int work = (flat & 7) * 64 + (flat >> 3);
    const int bh = work >> 4;               // 0..31
    const int qt = work & 15;               // 0..15
    const int b  = bh >> 4, hh = bh & 15;
    const int q0 = qt * 128;

    const unsigned short* Kp = Kd + (size_t)bh * N_ * D_;
    const unsigned short* Vp = Vt + (size_t)bh * D_ * N_;

    // Q B-fragments: q = q0 + wl*32 + q31, d = 16s + 8h + e
    const unsigned short* qp = Qd + ((size_t)bh * N_ + q0 + wl * 32 + q31) * D_;
    bf16x8 qf[4];
    #pragma unroll
    for (int s = 0; s < 4; ++s)
        qf[s] = *(const bf16x8*)(qp + 16 * s + 8 * h);

    // hoisted per-thread constants
    int go[4];
    #pragma unroll
    for (int s = 0; s < 4; ++s) go[s] = ((2 * s + h) ^ qsw) << 4;
    const int row0off = q31 * 128;
    const int row1off = (32 + q31) * 128;

    // staging addresses (per wave-group)
    const int rk = tl >> 3, pk = tl & 7;     // row 0..31, granule
    const unsigned char* kSrc = (const unsigned char*)Kp + rk * 128 + ((pk ^ (rk & 7)) << 4);
    const unsigned char* vSrc = (const unsigned char*)Vp + (size_t)rk * (N_ * 2) + ((pk ^ (rk & 7)) << 4);
    unsigned char* kDstA = Kbuf[wg][0] + tl * 16;
    unsigned char* kDstB = Kbuf[wg][1] + tl * 16;
    unsigned char* vDstA = Vbuf[wg][0] + tl * 16;
    unsigned char* vDstB = Vbuf[wg][1] + tl * 16;
    const unsigned char* kb0 = Kbuf[wg][0];
    const unsigned char* kb1 = Kbuf[wg][1];
    const unsigned char* vb0 = Vbuf[wg][0];
    const unsigned char* vb1 = Vbuf[wg][1];

    float m_run = -1e30f, l_run = 0.f;
    f32x16 oc0 = 0.f, oc1 = 0.f;

    auto stage = [&](unsigned char* kD, unsigned char* vD, int kt) {
        async16(kSrc + (size_t)kt * 8192, kD);
        async16(kSrc + (size_t)kt * 8192 + 4096, kD + 4096);           // rows 32..63
        async16(vSrc + (size_t)kt * 128, vD);
        async16(vSrc + 32 * (size_t)(N_ * 2) + (size_t)kt * 128, vD + 4096);
    };

    const int kt0 = wg * 16, ktEnd = kt0 + 16;
    stage(kDstA, vDstA, kt0);
    __syncthreads();

    auto tile_body = [&](const unsigned char* kbase, const unsigned char* vbase,
                         unsigned char* kDstN, unsigned char* vDstN, int ktNext) {
        if (ktNext < ktEnd) stage(kDstN, vDstN, ktNext);

        // ---- S^T = K * Q^T : 2 key-blocks x 4 d-slices ----
        f32x16 st0 = 0.f, st1 = 0.f;
        const unsigned char* krow0 = kbase + row0off;
        const unsigned char* krow1 = kbase + row1off;
        __builtin_amdgcn_s_setprio(1);
        #pragma unroll
        for (int s = 0; s < 4; ++s) {
            bf16x8 a0 = *(const bf16x8*)(krow0 + go[s]);
            bf16x8 a1 = *(const bf16x8*)(krow1 + go[s]);
            st0 = __builtin_amdgcn_mfma_f32_32x32x16_bf16(a0, qf[s], st0, 0, 0, 0);
            st1 = __builtin_amdgcn_mfma_f32_32x32x16_bf16(a1, qf[s], st1, 0, 0, 0);
        }
        __builtin_amdgcn_s_setprio(0);

        // ---- column max: vector max + tree + 1 cross-lane (xor 32) ----
        f32x16 mm;
        #pragma unroll
        for (int r = 0; r < 16; ++r) mm[r] = fmaxf(st0[r], st1[r]);
        float a0 = fmaxf(fmaxf(mm[0], mm[1]), mm[2]);
        float a1 = fmaxf(fmaxf(mm[3], mm[4]), mm[5]);
        float a2 = fmaxf(fmaxf(mm[6], mm[7]), mm[8]);
        float a3 = fmaxf(fmaxf(mm[9], mm[10]), mm[11]);
        float a4 = fmaxf(fmaxf(mm[12], mm[13]), mm[14]);
        float mx = fmaxf(fmaxf(fmaxf(a0, a1), fmaxf(a2, a3)), fmaxf(a4, mm[15]));
        mx = fmaxf(mx, __shfl_xor(mx, 32));

        // ---- defer-max (THR = 8 in log2 domain) ----
        const bool defer = __all(mx <= m_run + 8.f);
        if (!defer) {
            const float nm = fmaxf(m_run, mx);
            const float corr = fexp2(m_run - nm);
            m_run = nm;
            oc0 *= corr;
            oc1 *= corr;
            l_run *= corr;
        }
        #pragma unroll
        for (int r = 0; r < 16; ++r) {
            st0[r] = fexp2(st0[r] - m_run);
            st1[r] = fexp2(st1[r] - m_run);
        }

        // ---- denominator: vector sum + 1 cross-lane ----
        f32x16 sv = st0 + st1;
        float ts = ((sv[0] + sv[1]) + (sv[2] + sv[3])) + ((sv[4] + sv[5]) + (sv[6] + sv[7]))
                 + ((sv[8] + sv[9]) + (sv[10] + sv[11])) + ((sv[12] + sv[13]) + (sv[14] + sv[15]));
        ts += __shfl_xor(ts, 32);
        l_run += ts;

        // ---- pack P quads -> dwords (truncate to bf16) ----
        unsigned int pkd[2][4][2];
        #pragma unroll
        for (int m = 0; m < 4; ++m)
            #pragma unroll
            for (int j = 0; j < 2; ++j) {
                pkd[0][m][j] = __byte_perm(__float_as_uint(st0[4*m + 2*j]),
                                           __float_as_uint(st0[4*m + 2*j + 1]), 0x7632);
                pkd[1][m][j] = __byte_perm(__float_as_uint(st1[4*m + 2*j]),
                                           __float_as_uint(st1[4*m + 2*j + 1]), 0x7632);
            }

        // ---- permlane32_swap: (pk[2u], pk[2u+1]) -> (quadA, quadB) of pb[s=2kb+u] ----
        #pragma unroll
        for (int kb = 0; kb < 2; ++kb)
            #pragma unroll
            for (int u = 0; u < 2; ++u)
                #pragma unroll
                for (int j = 0; j < 2; ++j)
                    asm("v_permlane32_swap_b32 %0, %1"
                        : "+v"(pkd[kb][2*u][j]), "+v"(pkd[kb][2*u+1][j]));

        bf16x8 pb[4];
        #pragma unroll
        for (int s = 0; s < 4; ++s) {
            const int kb = s >> 1, u = s & 1;
            union { unsigned int d[4]; bf16x8 v; } uu;
            uu.d[0] = pkd[kb][2*u][0];
            uu.d[1] = pkd[kb][2*u][1];
            uu.d[2] = pkd[kb][2*u+1][0];
            uu.d[3] = pkd[kb][2*u+1][1];
            pb[s] = uu.v;
        }

        // ---- out^T += V^T * P : 2 d-blocks x 4 key-slices ----
        const unsigned char* vrow0 = vbase + row0off;
        const unsigned char* vrow1 = vbase + row1off;
        __builtin_amdgcn_s_setprio(1);
        #pragma unroll
        for (int s = 0; s < 4; ++s) {
            bf16x8 va0 = *(const bf16x8*)(vrow0 + go[s]);
            bf16x8 va1 = *(const bf16x8*)(vrow1 + go[s]);
            oc0 = __builtin_amdgcn_mfma_f32_32x32x16_bf16(va0, pb[s], oc0, 0, 0, 0);
            oc1 = __builtin_amdgcn_mfma_f32_32x32x16_bf16(va1, pb[s], oc1, 0, 0, 0);
        }
        __builtin_amdgcn_s_setprio(0);

        __syncthreads();   // drains vmcnt (stage done) + protects buffer swap
    };

    #pragma unroll 1
    for (int kt = kt0; kt < ktEnd; kt += 2) {
        tile_body(kb0, vb0, kDstB, vDstB, kt + 1);
        tile_body(kb1, vb1, kDstA, vDstA, kt + 2);
    }

    // ---- split-KV combine through LDS (reuse Kbuf; 256 slots x 40 f32) ----
    float* cb = (float*)&Kbuf[0][0][0];
    if (wg == 1) {
        float* s = cb + tl * 40;
        #pragma unroll
        for (int m = 0; m < 4; ++m) {
            f32x4 a, bq;
            #pragma unroll
            for (int i = 0; i < 4; ++i) { a[i] = oc0[4*m + i]; bq[i] = oc1[4*m + i]; }
            *(f32x4*)(s + 4 * m) = a;
            *(f32x4*)(s + 16 + 4 * m) = bq;
        }
        s[32] = m_run;
        s[33] = l_run;
    }
    __syncthreads();
    if (wg == 0) {
        const float* s = cb + tl * 40;
        float m1 = s[32], l1 = s[33];
        float mm = fmaxf(m_run, m1);
        float c0 = fexp2(m_run - mm);
        float c1 = fexp2(m1 - mm);
        float inv = 1.0f / (l_run * c0 + l1 * c1);
        const int q = q0 + wl * 32 + q31;
        _Float16* aop = AO + ((size_t)b * N_ + q) * C_ + hh * D_;
        #pragma unroll
        for (int m = 0; m < 4; ++m) {
            half4v o0, o1;
            #pragma unroll
            for (int i = 0; i < 4; ++i) {
                o0[i] = (_Float16)((oc0[4*m + i] * c0 + s[4*m + i] * c1) * inv);
                o1[i] = (_Float16)((oc1[4*m + i] * c0 + s[16 + 4*m + i] * c1) * inv);
            }
            *(half4v*)(aop + 8 * m + 4 * h) = o0;
            *(half4v*)(aop + 32 + 8 * m + 4 * h) = o1;
        }
    }
}

extern "C" void kernel_launch(void* const* d_in, const int* in_sizes, int n_in,
                              void* d_out, int out_size, void* d_ws, size_t ws_size,
                              hipStream_t stream) {
    const float* x      = (const float*)d_in[0];
    const float* w_qkv  = (const float*)d_in[1];
    const float* w_proj = (const float*)d_in[2];
    const float* b_proj = (const float*)d_in[3];
    float* out = (float*)d_out;

    const size_t hd = (size_t)B_ * H_ * N_ * D_;   // 4,194,304 elems
    unsigned short* Qd = (unsigned short*)d_ws;
    unsigned short* Kd = Qd + hd;
    unsigned short* Vt = Kd + hd;
    _Float16* AO  = (_Float16*)(Vt + hd);          // [B,N,C] f16
    _Float16* x16 = AO + hd;                       // [4096][1024]
    _Float16* wq16 = x16 + XN;                     // [3072][1024]
    _Float16* wp16 = wq16 + WQN;                   // [1024][1024]

    convert_f16<<<4096, 256, 0, stream>>>(x, w_qkv, w_proj, x16);
    gemm128<0><<<dim3(O3 / 128, M_ / 128), 256, 0, stream>>>(
        x16, wq16, Qd, Kd, Vt, nullptr, nullptr);
    attn_mfma<<<dim3(512), 512, 0, stream>>>(Qd, Kd, Vt, AO);
    gemm128<1><<<dim3(C_ / 128, M_ / 128), 256, 0, stream>>>(
        AO, wp16, nullptr, nullptr, nullptr, b_proj, out);
}